// Round 1
// baseline (599.620 us; speedup 1.0000x reference)
//
#include <hip/hip_runtime.h>
#include <math.h>

#define B_    32
#define A_    8400
#define M_    40
#define NC_   80
#define TOPK_ 10
#define EPS_  1e-9f

// ---------------------------------------------------------------- CIoU
__device__ __forceinline__ float ciou_f(float b1x1, float b1y1, float b1x2, float b1y2,
                                        float b2x1, float b2y1, float b2x2, float b2y2) {
    const float eps = 1e-7f;
    float w1 = b1x2 - b1x1, h1 = b1y2 - b1y1 + eps;
    float w2 = b2x2 - b2x1, h2 = b2y2 - b2y1 + eps;
    float iw = fminf(b1x2, b2x2) - fmaxf(b1x1, b2x1);
    float ih = fminf(b1y2, b2y2) - fmaxf(b1y1, b2y1);
    float inter = fmaxf(iw, 0.f) * fmaxf(ih, 0.f);
    float uni = w1 * h1 + w2 * h2 - inter + eps;
    float iou = inter / uni;
    float cw = fmaxf(b1x2, b2x2) - fminf(b1x1, b2x1);
    float ch = fmaxf(b1y2, b2y2) - fminf(b1y1, b2y1);
    float c2 = cw * cw + ch * ch + eps;
    float dx = b2x1 + b2x2 - b1x1 - b1x2;
    float dy = b2y1 + b2y2 - b1y1 - b1y2;
    float rho2 = (dx * dx + dy * dy) * 0.25f;
    float da = atanf(w2 / h2) - atanf(w1 / h1);
    float v = 0.4052847345693511f * da * da;       // 4/pi^2
    float alpha = v / (v - iou + 1.f + eps);       // stop_gradient irrelevant for fwd
    return iou - (rho2 / c2 + v * alpha);
}

// ------------------------------------------- K1: DFL decode -> pred boxes (grid units)
__global__ void k_predbox(const float* __restrict__ distri, const float* __restrict__ anc,
                          float* __restrict__ pb) {
    int idx = blockIdx.x * blockDim.x + threadIdx.x;
    if (idx >= B_ * A_) return;
    int a = idx % A_;
    const float* d = distri + (size_t)idx * 64;
    float dist[4];
#pragma unroll
    for (int s = 0; s < 4; s++) {
        float x[16];
#pragma unroll
        for (int j = 0; j < 16; j++) x[j] = d[s * 16 + j];
        float mx = x[0];
#pragma unroll
        for (int j = 1; j < 16; j++) mx = fmaxf(mx, x[j]);
        float se = 0.f, sd = 0.f;
#pragma unroll
        for (int j = 0; j < 16; j++) { float e = expf(x[j] - mx); se += e; sd += e * (float)j; }
        dist[s] = sd / se;
    }
    float ax = anc[2 * a], ay = anc[2 * a + 1];
    float* o = pb + (size_t)idx * 4;
    o[0] = ax - dist[0]; o[1] = ay - dist[1];
    o[2] = ax + dist[2]; o[3] = ay + dist[3];
}

// ------------------------------------------- K2: align / overlaps over [B,M,A], zero mask
__global__ void k_align(const float* __restrict__ scores, const float* __restrict__ pb,
                        const float* __restrict__ anc, const float* __restrict__ strd,
                        const float* __restrict__ gt, const float* __restrict__ mgt,
                        const int* __restrict__ glab,
                        float* __restrict__ align, float* __restrict__ ovr,
                        unsigned char* __restrict__ mpos) {
    size_t idx = (size_t)blockIdx.x * blockDim.x + threadIdx.x;
    if (idx >= (size_t)B_ * M_ * A_) return;
    int a = (int)(idx % A_);
    int bm = (int)(idx / A_);
    int b = bm / M_;
    mpos[idx] = 0;
    float al = 0.f, ov = 0.f;
    if (mgt[bm] > 0.f) {
        const float* g = gt + (size_t)bm * 4;
        float s = strd[a];
        float ax = anc[2 * a] * s, ay = anc[2 * a + 1] * s;
        if ((ax - g[0]) > EPS_ && (ay - g[1]) > EPS_ && (g[2] - ax) > EPS_ && (g[3] - ay) > EPS_) {
            const float* p = pb + ((size_t)b * A_ + a) * 4;
            float c = ciou_f(g[0], g[1], g[2], g[3], p[0] * s, p[1] * s, p[2] * s, p[3] * s);
            ov = fmaxf(c, 0.f);
            float sc = scores[((size_t)b * A_ + a) * NC_ + glab[bm]];
            float bs = 1.f / (1.f + expf(-sc));
            float o2 = ov * ov;
            al = sqrtf(bs) * o2 * o2 * o2;   // bs^0.5 * ov^6
        }
    }
    align[idx] = al;
    ovr[idx] = ov;
}

// ------------------------------------------- K3: top-10 per (b,m) -> mask_pos (+idx0 fallback)
__global__ void k_topk(const float* __restrict__ align, const float* __restrict__ anc,
                       const float* __restrict__ strd, const float* __restrict__ gt,
                       const float* __restrict__ mgt, unsigned char* __restrict__ mpos) {
    int bm = blockIdx.x;
    const float* arow = align + (size_t)bm * A_;
    __shared__ int   sel_idx[TOPK_];
    __shared__ float sel_val[TOPK_];
    __shared__ float red_v[256];
    __shared__ int   red_i[256];
    int tid = threadIdx.x;
    for (int k = 0; k < TOPK_; k++) {
        float best = -1.f; int bi = A_;
        for (int a = tid; a < A_; a += 256) {
            bool excl = false;
            for (int j = 0; j < k; j++) if (sel_idx[j] == a) excl = true;
            if (excl) continue;
            float v = arow[a];
            if (v > best) { best = v; bi = a; }   // ascending a => first occurrence kept
        }
        red_v[tid] = best; red_i[tid] = bi;
        __syncthreads();
        for (int s = 128; s > 0; s >>= 1) {
            if (tid < s) {
                float v2 = red_v[tid + s]; int i2 = red_i[tid + s];
                if (v2 > red_v[tid] || (v2 == red_v[tid] && i2 < red_i[tid])) {
                    red_v[tid] = v2; red_i[tid] = i2;
                }
            }
            __syncthreads();
        }
        if (tid == 0) { sel_idx[k] = red_i[0]; sel_val[k] = red_v[0]; }
        __syncthreads();
    }
    if (tid == 0) {
        int d = 0;
        for (int k = 0; k < TOPK_; k++) {
            if (sel_val[k] > EPS_) mpos[(size_t)bm * A_ + sel_idx[k]] = 1;
            else d++;
        }
        if (d > 0) {
            // dropped slots scatter onto index 0: mask_topk[0]=1, gated by mgt[b,m,0]
            float s0 = strd[0];
            float ax = anc[0] * s0, ay = anc[1] * s0;
            const float* g = gt + (size_t)bm * 4;
            bool in0 = (ax - g[0]) > EPS_ && (ay - g[1]) > EPS_ &&
                       (g[2] - ax) > EPS_ && (g[3] - ay) > EPS_;
            if (in0 && mgt[bm] > 0.f) mpos[(size_t)bm * A_ + 0] = 1;
        }
    }
}

// ------------------------------------------- K4: resolve multi-assignment, pick target gt
__global__ void k_resolve(unsigned char* __restrict__ mpos, const float* __restrict__ ovr,
                          const int* __restrict__ glab,
                          int* __restrict__ tgti, int* __restrict__ tlab,
                          unsigned char* __restrict__ fgm) {
    int idx = blockIdx.x * blockDim.x + threadIdx.x;
    if (idx >= B_ * A_) return;
    int b = idx / A_, a = idx % A_;
    size_t base = ((size_t)b * M_) * A_ + a;
    unsigned long long bits = 0ull;
    for (int m = 0; m < M_; m++)
        bits |= (unsigned long long)mpos[base + (size_t)m * A_] << m;
    int fg = __popcll(bits);
    int tgt = 0;
    if (fg > 1) {
        float bv = -1.f; int bm2 = 0;
        for (int m = 0; m < M_; m++) {
            float v = ovr[base + (size_t)m * A_];
            if (v > bv) { bv = v; bm2 = m; }        // first max, like jnp.argmax
        }
        for (int m = 0; m < M_; m++) mpos[base + (size_t)m * A_] = (m == bm2) ? 1 : 0;
        tgt = bm2; fg = 1;
    } else if (fg == 1) {
        tgt = __ffsll(bits) - 1;
    }
    tgti[idx] = tgt;
    tlab[idx] = max(glab[b * M_ + tgt], 0);
    fgm[idx] = (fg > 0) ? 1 : 0;
}

// ------------------------------------------- K5: per-gt pos_align / pos_overlap ratio
__global__ void k_posmax(const float* __restrict__ align, const float* __restrict__ ovr,
                         const unsigned char* __restrict__ mpos, float* __restrict__ rpos) {
    int bm = blockIdx.x;
    size_t base = (size_t)bm * A_;
    float pa = 0.f, po = 0.f;
    for (int a = threadIdx.x; a < A_; a += blockDim.x) {
        if (mpos[base + a]) { pa = fmaxf(pa, align[base + a]); po = fmaxf(po, ovr[base + a]); }
    }
    __shared__ float sa[256], so[256];
    sa[threadIdx.x] = pa; so[threadIdx.x] = po;
    __syncthreads();
    for (int s = 128; s > 0; s >>= 1) {
        if (threadIdx.x < s) {
            sa[threadIdx.x] = fmaxf(sa[threadIdx.x], sa[threadIdx.x + s]);
            so[threadIdx.x] = fmaxf(so[threadIdx.x], so[threadIdx.x + s]);
        }
        __syncthreads();
    }
    if (threadIdx.x == 0) rpos[bm] = so[0] / (sa[0] + EPS_);
}

// ------------------------------------------- K6: per-anchor norm + tss accumulation
__global__ void k_norm(const float* __restrict__ align, const float* __restrict__ rpos,
                       const int* __restrict__ tgti, const unsigned char* __restrict__ fgm,
                       float* __restrict__ normv, float* __restrict__ acc) {
    int idx = blockIdx.x * blockDim.x + threadIdx.x;
    float n = 0.f;
    if (idx < B_ * A_) {
        if (fgm[idx]) {
            int b = idx / A_, a = idx % A_;
            int m = tgti[idx];
            n = align[((size_t)b * M_ + m) * A_ + a] * rpos[b * M_ + m];
        }
        normv[idx] = n;
    }
    __shared__ float sh[256];
    sh[threadIdx.x] = n; __syncthreads();
    for (int s = 128; s > 0; s >>= 1) {
        if (threadIdx.x < s) sh[threadIdx.x] += sh[threadIdx.x + s];
        __syncthreads();
    }
    if (threadIdx.x == 0) atomicAdd(&acc[0], sh[0]);
}

// ------------------------------------------- K7: BCE over all logits
__global__ void k_cls(const float* __restrict__ scores, const int* __restrict__ tlab,
                      const float* __restrict__ normv, float* __restrict__ acc) {
    const size_t N = (size_t)B_ * A_ * NC_;
    float lsum = 0.f;
    for (size_t i = (size_t)blockIdx.x * blockDim.x + threadIdx.x; i < N;
         i += (size_t)gridDim.x * blockDim.x) {
        int c = (int)(i % NC_);
        size_t ba = i / NC_;
        float x = scores[i];
        float t = (c == tlab[ba]) ? normv[ba] : 0.f;
        lsum += fmaxf(x, 0.f) - x * t + log1pf(expf(-fabsf(x)));
    }
    __shared__ float sh[256];
    sh[threadIdx.x] = lsum; __syncthreads();
    for (int s = 128; s > 0; s >>= 1) {
        if (threadIdx.x < s) sh[threadIdx.x] += sh[threadIdx.x + s];
        __syncthreads();
    }
    if (threadIdx.x == 0) atomicAdd(&acc[1], sh[0]);
}

// ------------------------------------------- K8: CIoU loss + DFL loss for fg anchors
__global__ void k_boxdfl(const float* __restrict__ distri, const float* __restrict__ pb,
                         const float* __restrict__ anc, const float* __restrict__ strd,
                         const float* __restrict__ gt, const int* __restrict__ tgti,
                         const unsigned char* __restrict__ fgm, const float* __restrict__ normv,
                         float* __restrict__ acc) {
    int idx = blockIdx.x * blockDim.x + threadIdx.x;
    float liou = 0.f, ldfl = 0.f;
    if (idx < B_ * A_ && fgm[idx]) {
        int b = idx / A_, a = idx % A_;
        int m = tgti[idx];
        float w = normv[idx];
        float s = strd[a];
        const float* g = gt + ((size_t)b * M_ + m) * 4;
        float t0 = g[0] / s, t1 = g[1] / s, t2 = g[2] / s, t3 = g[3] / s;
        const float* p = pb + (size_t)idx * 4;
        float iou = ciou_f(p[0], p[1], p[2], p[3], t0, t1, t2, t3);
        liou = (1.f - iou) * w;
        float ax = anc[2 * a], ay = anc[2 * a + 1];
        float tg[4] = { ax - t0, ay - t1, t2 - ax, t3 - ay };
        const float* dd = distri + (size_t)idx * 64;
        float dfl = 0.f;
#pragma unroll
        for (int sd = 0; sd < 4; sd++) {
            float tv = fminf(fmaxf(tg[sd], 0.f), 14.99f);
            int tl = (int)tv;
            float wl = (float)(tl + 1) - tv;
            float wr = 1.f - wl;
            const float* xx = dd + sd * 16;
            float mx = xx[0];
#pragma unroll
            for (int j = 1; j < 16; j++) mx = fmaxf(mx, xx[j]);
            float se = 0.f;
#pragma unroll
            for (int j = 0; j < 16; j++) se += expf(xx[j] - mx);
            float lse = mx + logf(se);
            dfl += (lse - xx[tl]) * wl + (lse - xx[tl + 1]) * wr;
        }
        ldfl = dfl * 0.25f * w;
    }
    __shared__ float s1[256], s2[256];
    s1[threadIdx.x] = liou; s2[threadIdx.x] = ldfl;
    __syncthreads();
    for (int s = 128; s > 0; s >>= 1) {
        if (threadIdx.x < s) {
            s1[threadIdx.x] += s1[threadIdx.x + s];
            s2[threadIdx.x] += s2[threadIdx.x + s];
        }
        __syncthreads();
    }
    if (threadIdx.x == 0) { atomicAdd(&acc[2], s1[0]); atomicAdd(&acc[3], s2[0]); }
}

// ------------------------------------------- K9: finalize
__global__ void k_final(const float* __restrict__ acc, float* __restrict__ out) {
    if (threadIdx.x == 0) {
        float tss = fmaxf(acc[0], 1.f);
        out[0] = acc[2] / tss * 7.5f;   // loss_iou * HYP_BOX
        out[1] = acc[1] / tss * 0.5f;   // loss_cls * HYP_CLS
        out[2] = acc[3] / tss * 1.5f;   // loss_dfl * HYP_DFL
    }
}

extern "C" void kernel_launch(void* const* d_in, const int* in_sizes, int n_in,
                              void* d_out, int out_size, void* d_ws, size_t ws_size,
                              hipStream_t stream) {
    const float* scores = (const float*)d_in[0];   // [B,A,NC]
    const float* distri = (const float*)d_in[1];   // [B,A,64]
    const float* anc    = (const float*)d_in[2];   // [A,2]  (grid units)
    const float* strd   = (const float*)d_in[3];   // [A,1]
    const float* gtb    = (const float*)d_in[4];   // [B,M,4] (pixels)
    const float* mgt    = (const float*)d_in[5];   // [B,M]
    const int*   glab   = (const int*)d_in[6];     // [B,M]
    float* out = (float*)d_out;

    // workspace layout (~99 MiB)
    float* pb    = (float*)d_ws;                         // B*A*4
    float* align = pb + (size_t)B_ * A_ * 4;             // B*M*A
    float* ovr   = align + (size_t)B_ * M_ * A_;         // B*M*A
    float* rpos  = ovr + (size_t)B_ * M_ * A_;           // B*M
    float* normv = rpos + B_ * M_;                       // B*A
    float* acc   = normv + (size_t)B_ * A_;              // 4
    int*   tgti  = (int*)(acc + 4);                      // B*A
    int*   tlab  = tgti + (size_t)B_ * A_;               // B*A
    unsigned char* fgm  = (unsigned char*)(tlab + (size_t)B_ * A_); // B*A
    unsigned char* mpos = fgm + (size_t)B_ * A_;         // B*M*A

    hipMemsetAsync(acc, 0, 4 * sizeof(float), stream);

    const int nBA = B_ * A_;
    const size_t nBMA = (size_t)B_ * M_ * A_;

    k_predbox<<<(nBA + 255) / 256, 256, 0, stream>>>(distri, anc, pb);
    k_align<<<(int)((nBMA + 255) / 256), 256, 0, stream>>>(scores, pb, anc, strd, gtb, mgt,
                                                           glab, align, ovr, mpos);
    k_topk<<<B_ * M_, 256, 0, stream>>>(align, anc, strd, gtb, mgt, mpos);
    k_resolve<<<(nBA + 255) / 256, 256, 0, stream>>>(mpos, ovr, glab, tgti, tlab, fgm);
    k_posmax<<<B_ * M_, 256, 0, stream>>>(align, ovr, mpos, rpos);
    k_norm<<<(nBA + 255) / 256, 256, 0, stream>>>(align, rpos, tgti, fgm, normv, acc);
    k_cls<<<4096, 256, 0, stream>>>(scores, tlab, normv, acc);
    k_boxdfl<<<(nBA + 255) / 256, 256, 0, stream>>>(distri, pb, anc, strd, gtb, tgti,
                                                    fgm, normv, acc);
    k_final<<<1, 64, 0, stream>>>(acc, out);
}

// Round 2
// 424.657 us; speedup vs baseline: 1.4120x; 1.4120x over previous
//
#include <hip/hip_runtime.h>
#include <math.h>

#define B_    32
#define A_    8400
#define M_    40
#define NC_   80
#define TOPK_ 10
#define EPS_  1e-9f

// ---------------------------------------------------------------- CIoU
__device__ __forceinline__ float ciou_f(float b1x1, float b1y1, float b1x2, float b1y2,
                                        float b2x1, float b2y1, float b2x2, float b2y2) {
    const float eps = 1e-7f;
    float w1 = b1x2 - b1x1, h1 = b1y2 - b1y1 + eps;
    float w2 = b2x2 - b2x1, h2 = b2y2 - b2y1 + eps;
    float iw = fminf(b1x2, b2x2) - fmaxf(b1x1, b2x1);
    float ih = fminf(b1y2, b2y2) - fmaxf(b1y1, b2y1);
    float inter = fmaxf(iw, 0.f) * fmaxf(ih, 0.f);
    float uni = w1 * h1 + w2 * h2 - inter + eps;
    float iou = inter / uni;
    float cw = fmaxf(b1x2, b2x2) - fminf(b1x1, b2x1);
    float ch = fmaxf(b1y2, b2y2) - fminf(b1y1, b2y1);
    float c2 = cw * cw + ch * ch + eps;
    float dx = b2x1 + b2x2 - b1x1 - b1x2;
    float dy = b2y1 + b2y2 - b1y1 - b1y2;
    float rho2 = (dx * dx + dy * dy) * 0.25f;
    float da = atanf(w2 / h2) - atanf(w1 / h1);
    float v = 0.4052847345693511f * da * da;       // 4/pi^2
    float alpha = v / (v - iou + 1.f + eps);
    return iou - (rho2 / c2 + v * alpha);
}

// (value desc, index asc) total order
__device__ __forceinline__ bool pair_gt(float v1, int i1, float v2, int i2) {
    return (v1 > v2) || (v1 == v2 && i1 < i2);
}

// ------------------------------------------- K1: DFL decode -> pred boxes (grid units)
__global__ void k_predbox(const float* __restrict__ distri, const float* __restrict__ anc,
                          float* __restrict__ pb) {
    int idx = blockIdx.x * blockDim.x + threadIdx.x;
    if (idx >= B_ * A_) return;
    int a = idx % A_;
    const float* d = distri + (size_t)idx * 64;
    float dist[4];
#pragma unroll
    for (int s = 0; s < 4; s++) {
        float x[16];
#pragma unroll
        for (int j = 0; j < 16; j++) x[j] = d[s * 16 + j];
        float mx = x[0];
#pragma unroll
        for (int j = 1; j < 16; j++) mx = fmaxf(mx, x[j]);
        float se = 0.f, sd = 0.f;
#pragma unroll
        for (int j = 0; j < 16; j++) { float e = expf(x[j] - mx); se += e; sd += e * (float)j; }
        dist[s] = sd / se;
    }
    float ax = anc[2 * a], ay = anc[2 * a + 1];
    float* o = pb + (size_t)idx * 4;
    o[0] = ax - dist[0]; o[1] = ay - dist[1];
    o[2] = ax + dist[2]; o[3] = ay + dist[3];
}

// ------------------------------------------- K2: align / overlaps over [B,M,A], zero mask
__global__ void k_align(const float* __restrict__ scores, const float* __restrict__ pb,
                        const float* __restrict__ anc, const float* __restrict__ strd,
                        const float* __restrict__ gt, const float* __restrict__ mgt,
                        const int* __restrict__ glab,
                        float* __restrict__ align, float* __restrict__ ovr,
                        unsigned char* __restrict__ mpos) {
    size_t idx = (size_t)blockIdx.x * blockDim.x + threadIdx.x;
    if (idx >= (size_t)B_ * M_ * A_) return;
    int a = (int)(idx % A_);
    int bm = (int)(idx / A_);
    int b = bm / M_;
    mpos[idx] = 0;
    float al = 0.f, ov = 0.f;
    if (mgt[bm] > 0.f) {
        const float* g = gt + (size_t)bm * 4;
        float s = strd[a];
        float ax = anc[2 * a] * s, ay = anc[2 * a + 1] * s;
        if ((ax - g[0]) > EPS_ && (ay - g[1]) > EPS_ && (g[2] - ax) > EPS_ && (g[3] - ay) > EPS_) {
            const float* p = pb + ((size_t)b * A_ + a) * 4;
            float c = ciou_f(g[0], g[1], g[2], g[3], p[0] * s, p[1] * s, p[2] * s, p[3] * s);
            ov = fmaxf(c, 0.f);
            float sc = scores[((size_t)b * A_ + a) * NC_ + glab[bm]];
            float bs = 1.f / (1.f + expf(-sc));
            float o2 = ov * ov;
            al = sqrtf(bs) * o2 * o2 * o2;   // bs^0.5 * ov^6
        }
    }
    align[idx] = al;
    ovr[idx] = ov;
}

// ------------------------------------------- K3: single-pass top-10 per (b,m)
// Per-thread register top-10 (bubble-insert network, static indexing), then
// 8-level LDS tree merge using merged[k] = min_{i+j=k} max(A[i],B[j]).
__global__ __launch_bounds__(256) void k_topk(const float* __restrict__ align,
                                              const float* __restrict__ anc,
                                              const float* __restrict__ strd,
                                              const float* __restrict__ gt,
                                              const float* __restrict__ mgt,
                                              unsigned char* __restrict__ mpos) {
    int bm = blockIdx.x;
    const float* arow = align + (size_t)bm * A_;
    int tid = threadIdx.x;

    float tv[TOPK_]; int ti[TOPK_];
#pragma unroll
    for (int k = 0; k < TOPK_; k++) { tv[k] = -1.f; ti[k] = 0x7fffffff; }

    for (int a = tid; a < A_; a += 256) {
        float v = arow[a];
        if (pair_gt(v, a, tv[TOPK_ - 1], ti[TOPK_ - 1])) {
            float cv = v; int ci = a;
#pragma unroll
            for (int k = 0; k < TOPK_; k++) {
                bool g = pair_gt(cv, ci, tv[k], ti[k]);
                float ov = tv[k]; int oi = ti[k];
                tv[k] = g ? cv : ov;  ti[k] = g ? ci : oi;
                cv    = g ? ov : cv;  ci    = g ? oi : ci;
            }
        }
    }

    __shared__ float sv[256 * TOPK_];
    __shared__ int   si[256 * TOPK_];
#pragma unroll
    for (int k = 0; k < TOPK_; k++) { sv[tid * TOPK_ + k] = tv[k]; si[tid * TOPK_ + k] = ti[k]; }
    __syncthreads();

    for (int s = 128; s >= 1; s >>= 1) {
        if (tid < s) {
            int pbase = (tid + s) * TOPK_;
            float bv[TOPK_]; int bi[TOPK_];
#pragma unroll
            for (int k = 0; k < TOPK_; k++) { bv[k] = sv[pbase + k]; bi[k] = si[pbase + k]; }
            float mv[TOPK_]; int mi[TOPK_];
#pragma unroll
            for (int k = 0; k < TOPK_; k++) {
                // i = 0 term
                bool g0 = pair_gt(tv[0], ti[0], bv[k], bi[k]);
                float cv = g0 ? tv[0] : bv[k];
                int   ci = g0 ? ti[0] : bi[k];
#pragma unroll
                for (int i = 1; i <= k; i++) {
                    bool g = pair_gt(tv[i], ti[i], bv[k - i], bi[k - i]);
                    float xv = g ? tv[i] : bv[k - i];
                    int   xi = g ? ti[i] : bi[k - i];
                    bool l = pair_gt(cv, ci, xv, xi);   // keep the smaller (min)
                    cv = l ? xv : cv; ci = l ? xi : ci;
                }
                mv[k] = cv; mi[k] = ci;
            }
#pragma unroll
            for (int k = 0; k < TOPK_; k++) {
                tv[k] = mv[k]; ti[k] = mi[k];
                sv[tid * TOPK_ + k] = tv[k]; si[tid * TOPK_ + k] = ti[k];
            }
        }
        __syncthreads();
    }

    if (tid == 0) {
        int d = 0;
#pragma unroll
        for (int k = 0; k < TOPK_; k++) {
            if (tv[k] > EPS_) mpos[(size_t)bm * A_ + ti[k]] = 1;
            else d++;
        }
        if (d > 0) {
            // dropped slots scatter onto index 0: mask_topk[0]=1, gated by mgt[b,m,0]
            float s0 = strd[0];
            float ax = anc[0] * s0, ay = anc[1] * s0;
            const float* g = gt + (size_t)bm * 4;
            bool in0 = (ax - g[0]) > EPS_ && (ay - g[1]) > EPS_ &&
                       (g[2] - ax) > EPS_ && (g[3] - ay) > EPS_;
            if (in0 && mgt[bm] > 0.f) mpos[(size_t)bm * A_ + 0] = 1;
        }
    }
}

// ------------------------------------------- K4: resolve multi-assignment, pick target gt
__global__ void k_resolve(unsigned char* __restrict__ mpos, const float* __restrict__ ovr,
                          const int* __restrict__ glab,
                          int* __restrict__ tgti, int* __restrict__ tlab,
                          unsigned char* __restrict__ fgm) {
    int idx = blockIdx.x * blockDim.x + threadIdx.x;
    if (idx >= B_ * A_) return;
    int b = idx / A_, a = idx % A_;
    size_t base = ((size_t)b * M_) * A_ + a;
    unsigned long long bits = 0ull;
    for (int m = 0; m < M_; m++)
        bits |= (unsigned long long)mpos[base + (size_t)m * A_] << m;
    int fg = __popcll(bits);
    int tgt = 0;
    if (fg > 1) {
        float bv = -1.f; int bm2 = 0;
        for (int m = 0; m < M_; m++) {
            float v = ovr[base + (size_t)m * A_];
            if (v > bv) { bv = v; bm2 = m; }        // first max, like jnp.argmax
        }
        for (int m = 0; m < M_; m++) mpos[base + (size_t)m * A_] = (m == bm2) ? 1 : 0;
        tgt = bm2; fg = 1;
    } else if (fg == 1) {
        tgt = __ffsll(bits) - 1;
    }
    tgti[idx] = tgt;
    tlab[idx] = max(glab[b * M_ + tgt], 0);
    fgm[idx] = (fg > 0) ? 1 : 0;
}

// ------------------------------------------- K5: per-gt pos_align / pos_overlap ratio
__global__ void k_posmax(const float* __restrict__ align, const float* __restrict__ ovr,
                         const unsigned char* __restrict__ mpos, float* __restrict__ rpos) {
    int bm = blockIdx.x;
    size_t base = (size_t)bm * A_;
    float pa = 0.f, po = 0.f;
    for (int a = threadIdx.x; a < A_; a += blockDim.x) {
        if (mpos[base + a]) { pa = fmaxf(pa, align[base + a]); po = fmaxf(po, ovr[base + a]); }
    }
    __shared__ float sa[256], so[256];
    sa[threadIdx.x] = pa; so[threadIdx.x] = po;
    __syncthreads();
    for (int s = 128; s > 0; s >>= 1) {
        if (threadIdx.x < s) {
            sa[threadIdx.x] = fmaxf(sa[threadIdx.x], sa[threadIdx.x + s]);
            so[threadIdx.x] = fmaxf(so[threadIdx.x], so[threadIdx.x + s]);
        }
        __syncthreads();
    }
    if (threadIdx.x == 0) rpos[bm] = so[0] / (sa[0] + EPS_);
}

// ------------------------------------------- K6: per-anchor norm + tss accumulation
__global__ void k_norm(const float* __restrict__ align, const float* __restrict__ rpos,
                       const int* __restrict__ tgti, const unsigned char* __restrict__ fgm,
                       float* __restrict__ normv, float* __restrict__ acc) {
    int idx = blockIdx.x * blockDim.x + threadIdx.x;
    float n = 0.f;
    if (idx < B_ * A_) {
        if (fgm[idx]) {
            int b = idx / A_, a = idx % A_;
            int m = tgti[idx];
            n = align[((size_t)b * M_ + m) * A_ + a] * rpos[b * M_ + m];
        }
        normv[idx] = n;
    }
    __shared__ float sh[256];
    sh[threadIdx.x] = n; __syncthreads();
    for (int s = 128; s > 0; s >>= 1) {
        if (threadIdx.x < s) sh[threadIdx.x] += sh[threadIdx.x + s];
        __syncthreads();
    }
    if (threadIdx.x == 0) atomicAdd(&acc[0], sh[0]);
}

// ------------------------------------------- K7: BCE over all logits
__global__ void k_cls(const float* __restrict__ scores, const int* __restrict__ tlab,
                      const float* __restrict__ normv, float* __restrict__ acc) {
    const size_t N = (size_t)B_ * A_ * NC_;
    float lsum = 0.f;
    for (size_t i = (size_t)blockIdx.x * blockDim.x + threadIdx.x; i < N;
         i += (size_t)gridDim.x * blockDim.x) {
        int c = (int)(i % NC_);
        size_t ba = i / NC_;
        float x = scores[i];
        float t = (c == tlab[ba]) ? normv[ba] : 0.f;
        lsum += fmaxf(x, 0.f) - x * t + log1pf(expf(-fabsf(x)));
    }
    __shared__ float sh[256];
    sh[threadIdx.x] = lsum; __syncthreads();
    for (int s = 128; s > 0; s >>= 1) {
        if (threadIdx.x < s) sh[threadIdx.x] += sh[threadIdx.x + s];
        __syncthreads();
    }
    if (threadIdx.x == 0) atomicAdd(&acc[1], sh[0]);
}

// ------------------------------------------- K8: CIoU loss + DFL loss for fg anchors
__global__ void k_boxdfl(const float* __restrict__ distri, const float* __restrict__ pb,
                         const float* __restrict__ anc, const float* __restrict__ strd,
                         const float* __restrict__ gt, const int* __restrict__ tgti,
                         const unsigned char* __restrict__ fgm, const float* __restrict__ normv,
                         float* __restrict__ acc) {
    int idx = blockIdx.x * blockDim.x + threadIdx.x;
    float liou = 0.f, ldfl = 0.f;
    if (idx < B_ * A_ && fgm[idx]) {
        int b = idx / A_, a = idx % A_;
        int m = tgti[idx];
        float w = normv[idx];
        float s = strd[a];
        const float* g = gt + ((size_t)b * M_ + m) * 4;
        float t0 = g[0] / s, t1 = g[1] / s, t2 = g[2] / s, t3 = g[3] / s;
        const float* p = pb + (size_t)idx * 4;
        float iou = ciou_f(p[0], p[1], p[2], p[3], t0, t1, t2, t3);
        liou = (1.f - iou) * w;
        float ax = anc[2 * a], ay = anc[2 * a + 1];
        float tg[4] = { ax - t0, ay - t1, t2 - ax, t3 - ay };
        const float* dd = distri + (size_t)idx * 64;
        float dfl = 0.f;
#pragma unroll
        for (int sd = 0; sd < 4; sd++) {
            float tvv = fminf(fmaxf(tg[sd], 0.f), 14.99f);
            int tl = (int)tvv;
            float wl = (float)(tl + 1) - tvv;
            float wr = 1.f - wl;
            const float* xx = dd + sd * 16;
            float mx = xx[0];
#pragma unroll
            for (int j = 1; j < 16; j++) mx = fmaxf(mx, xx[j]);
            float se = 0.f;
#pragma unroll
            for (int j = 0; j < 16; j++) se += expf(xx[j] - mx);
            float lse = mx + logf(se);
            dfl += (lse - xx[tl]) * wl + (lse - xx[tl + 1]) * wr;
        }
        ldfl = dfl * 0.25f * w;
    }
    __shared__ float s1[256], s2[256];
    s1[threadIdx.x] = liou; s2[threadIdx.x] = ldfl;
    __syncthreads();
    for (int s = 128; s > 0; s >>= 1) {
        if (threadIdx.x < s) {
            s1[threadIdx.x] += s1[threadIdx.x + s];
            s2[threadIdx.x] += s2[threadIdx.x + s];
        }
        __syncthreads();
    }
    if (threadIdx.x == 0) { atomicAdd(&acc[2], s1[0]); atomicAdd(&acc[3], s2[0]); }
}

// ------------------------------------------- K9: finalize
__global__ void k_final(const float* __restrict__ acc, float* __restrict__ out) {
    if (threadIdx.x == 0) {
        float tss = fmaxf(acc[0], 1.f);
        out[0] = acc[2] / tss * 7.5f;   // loss_iou * HYP_BOX
        out[1] = acc[1] / tss * 0.5f;   // loss_cls * HYP_CLS
        out[2] = acc[3] / tss * 1.5f;   // loss_dfl * HYP_DFL
    }
}

extern "C" void kernel_launch(void* const* d_in, const int* in_sizes, int n_in,
                              void* d_out, int out_size, void* d_ws, size_t ws_size,
                              hipStream_t stream) {
    const float* scores = (const float*)d_in[0];   // [B,A,NC]
    const float* distri = (const float*)d_in[1];   // [B,A,64]
    const float* anc    = (const float*)d_in[2];   // [A,2]  (grid units)
    const float* strd   = (const float*)d_in[3];   // [A,1]
    const float* gtb    = (const float*)d_in[4];   // [B,M,4] (pixels)
    const float* mgt    = (const float*)d_in[5];   // [B,M]
    const int*   glab   = (const int*)d_in[6];     // [B,M]
    float* out = (float*)d_out;

    // workspace layout (~99 MiB)
    float* pb    = (float*)d_ws;                         // B*A*4
    float* align = pb + (size_t)B_ * A_ * 4;             // B*M*A
    float* ovr   = align + (size_t)B_ * M_ * A_;         // B*M*A
    float* rpos  = ovr + (size_t)B_ * M_ * A_;           // B*M
    float* normv = rpos + B_ * M_;                       // B*A
    float* acc   = normv + (size_t)B_ * A_;              // 4
    int*   tgti  = (int*)(acc + 4);                      // B*A
    int*   tlab  = tgti + (size_t)B_ * A_;               // B*A
    unsigned char* fgm  = (unsigned char*)(tlab + (size_t)B_ * A_); // B*A
    unsigned char* mpos = fgm + (size_t)B_ * A_;         // B*M*A

    hipMemsetAsync(acc, 0, 4 * sizeof(float), stream);

    const int nBA = B_ * A_;
    const size_t nBMA = (size_t)B_ * M_ * A_;

    k_predbox<<<(nBA + 255) / 256, 256, 0, stream>>>(distri, anc, pb);
    k_align<<<(int)((nBMA + 255) / 256), 256, 0, stream>>>(scores, pb, anc, strd, gtb, mgt,
                                                           glab, align, ovr, mpos);
    k_topk<<<B_ * M_, 256, 0, stream>>>(align, anc, strd, gtb, mgt, mpos);
    k_resolve<<<(nBA + 255) / 256, 256, 0, stream>>>(mpos, ovr, glab, tgti, tlab, fgm);
    k_posmax<<<B_ * M_, 256, 0, stream>>>(align, ovr, mpos, rpos);
    k_norm<<<(nBA + 255) / 256, 256, 0, stream>>>(align, rpos, tgti, fgm, normv, acc);
    k_cls<<<4096, 256, 0, stream>>>(scores, tlab, normv, acc);
    k_boxdfl<<<(nBA + 255) / 256, 256, 0, stream>>>(distri, pb, anc, strd, gtb, tgti,
                                                    fgm, normv, acc);
    k_final<<<1, 64, 0, stream>>>(acc, out);
}

// Round 3
// 390.042 us; speedup vs baseline: 1.5373x; 1.0887x over previous
//
#include <hip/hip_runtime.h>
#include <math.h>

#define B_    32
#define A_    8400
#define M_    40
#define NC_   80
#define TOPK_ 10
#define EPS_  1e-9f

// ---------------------------------------------------------------- CIoU
__device__ __forceinline__ float ciou_f(float b1x1, float b1y1, float b1x2, float b1y2,
                                        float b2x1, float b2y1, float b2x2, float b2y2) {
    const float eps = 1e-7f;
    float w1 = b1x2 - b1x1, h1 = b1y2 - b1y1 + eps;
    float w2 = b2x2 - b2x1, h2 = b2y2 - b2y1 + eps;
    float iw = fminf(b1x2, b2x2) - fmaxf(b1x1, b2x1);
    float ih = fminf(b1y2, b2y2) - fmaxf(b1y1, b2y1);
    float inter = fmaxf(iw, 0.f) * fmaxf(ih, 0.f);
    float uni = w1 * h1 + w2 * h2 - inter + eps;
    float iou = inter / uni;
    float cw = fmaxf(b1x2, b2x2) - fminf(b1x1, b2x1);
    float ch = fmaxf(b1y2, b2y2) - fminf(b1y1, b2y1);
    float c2 = cw * cw + ch * ch + eps;
    float dx = b2x1 + b2x2 - b1x1 - b1x2;
    float dy = b2y1 + b2y2 - b1y1 - b1y2;
    float rho2 = (dx * dx + dy * dy) * 0.25f;
    float da = atanf(w2 / h2) - atanf(w1 / h1);
    float v = 0.4052847345693511f * da * da;       // 4/pi^2
    float alpha = v / (v - iou + 1.f + eps);
    return iou - (rho2 / c2 + v * alpha);
}

// masked overlap at (b, gt-box g, anchor a); 0 if anchor center outside box
__device__ __forceinline__ float ov_at(const float* __restrict__ pb,
                                       const float* __restrict__ anc,
                                       const float* __restrict__ strd,
                                       float g0, float g1, float g2, float g3,
                                       int b, int a) {
    float s = strd[a];
    float ax = anc[2 * a] * s, ay = anc[2 * a + 1] * s;
    if (!((ax - g0) > EPS_ && (ay - g1) > EPS_ && (g2 - ax) > EPS_ && (g3 - ay) > EPS_))
        return 0.f;
    const float* p = pb + ((size_t)b * A_ + a) * 4;
    float c = ciou_f(g0, g1, g2, g3, p[0] * s, p[1] * s, p[2] * s, p[3] * s);
    return fmaxf(c, 0.f);
}

// (value desc, index asc) total order
__device__ __forceinline__ bool pair_gt(float v1, int i1, float v2, int i2) {
    return (v1 > v2) || (v1 == v2 && i1 < i2);
}

// ------------------------------------------- K1: DFL decode -> pred boxes (grid units)
__global__ __launch_bounds__(256) void k_predbox(const float* __restrict__ distri,
                                                 const float* __restrict__ anc,
                                                 float* __restrict__ pb) {
    int idx = blockIdx.x * blockDim.x + threadIdx.x;
    if (idx >= B_ * A_) return;
    int a = idx % A_;
    const float4* d4 = (const float4*)(distri + (size_t)idx * 64);
    float dist[4];
#pragma unroll
    for (int s = 0; s < 4; s++) {
        float4 q0 = d4[s * 4 + 0], q1 = d4[s * 4 + 1], q2 = d4[s * 4 + 2], q3 = d4[s * 4 + 3];
        float x[16] = { q0.x, q0.y, q0.z, q0.w, q1.x, q1.y, q1.z, q1.w,
                        q2.x, q2.y, q2.z, q2.w, q3.x, q3.y, q3.z, q3.w };
        float mx = x[0];
#pragma unroll
        for (int j = 1; j < 16; j++) mx = fmaxf(mx, x[j]);
        float se = 0.f, sd = 0.f;
#pragma unroll
        for (int j = 0; j < 16; j++) { float e = __expf(x[j] - mx); se += e; sd += e * (float)j; }
        dist[s] = sd / se;
    }
    float ax = anc[2 * a], ay = anc[2 * a + 1];
    float4* o = (float4*)(pb + (size_t)idx * 4);
    *o = make_float4(ax - dist[0], ay - dist[1], ax + dist[2], ay + dist[3]);
}

// ------------------------------------------- K2: fused align + single-pass top-10
// One block per (b,m). Computes align on the fly, register top-10 + LDS tree merge,
// emits ONLY the selection bitmask (2x u32 per anchor, bit m set).
__global__ __launch_bounds__(256) void k_aligntopk(
    const float* __restrict__ scores, const float* __restrict__ pb,
    const float* __restrict__ anc, const float* __restrict__ strd,
    const float* __restrict__ gt, const float* __restrict__ mgt,
    const int* __restrict__ glab, unsigned int* __restrict__ abits) {
    int bm = blockIdx.x;
    if (mgt[bm] <= 0.f) return;                 // row all-zero: no selection, no fallback
    int b = bm / M_, m = bm % M_;
    int lab = glab[bm];
    const float g0 = gt[bm * 4 + 0], g1 = gt[bm * 4 + 1];
    const float g2 = gt[bm * 4 + 2], g3 = gt[bm * 4 + 3];
    int tid = threadIdx.x;

    float tv[TOPK_]; int ti[TOPK_];
#pragma unroll
    for (int k = 0; k < TOPK_; k++) { tv[k] = -1.f; ti[k] = 0x7fffffff; }

    for (int a = tid; a < A_; a += 256) {
        float ov = ov_at(pb, anc, strd, g0, g1, g2, g3, b, a);
        float al = 0.f;
        if (ov > 0.f) {
            float sc = scores[((size_t)b * A_ + a) * NC_ + lab];
            float bs = 1.f / (1.f + expf(-sc));
            float o2 = ov * ov;
            al = sqrtf(bs) * o2 * o2 * o2;      // bs^0.5 * ov^6
        }
        if (pair_gt(al, a, tv[TOPK_ - 1], ti[TOPK_ - 1])) {
            float cv = al; int ci = a;
#pragma unroll
            for (int k = 0; k < TOPK_; k++) {
                bool g = pair_gt(cv, ci, tv[k], ti[k]);
                float ovv = tv[k]; int oi = ti[k];
                tv[k] = g ? cv : ovv;  ti[k] = g ? ci : oi;
                cv    = g ? ovv : cv;  ci    = g ? oi : ci;
            }
        }
    }

    __shared__ float sv[256 * TOPK_];
    __shared__ int   si[256 * TOPK_];
#pragma unroll
    for (int k = 0; k < TOPK_; k++) { sv[tid * TOPK_ + k] = tv[k]; si[tid * TOPK_ + k] = ti[k]; }
    __syncthreads();

    for (int s = 128; s >= 1; s >>= 1) {
        if (tid < s) {
            int pbase = (tid + s) * TOPK_;
            float bv[TOPK_]; int bi[TOPK_];
#pragma unroll
            for (int k = 0; k < TOPK_; k++) { bv[k] = sv[pbase + k]; bi[k] = si[pbase + k]; }
            float mv[TOPK_]; int mi[TOPK_];
#pragma unroll
            for (int k = 0; k < TOPK_; k++) {
                bool g0b = pair_gt(tv[0], ti[0], bv[k], bi[k]);
                float cv = g0b ? tv[0] : bv[k];
                int   ci = g0b ? ti[0] : bi[k];
#pragma unroll
                for (int i = 1; i <= k; i++) {
                    bool g = pair_gt(tv[i], ti[i], bv[k - i], bi[k - i]);
                    float xv = g ? tv[i] : bv[k - i];
                    int   xi = g ? ti[i] : bi[k - i];
                    bool l = pair_gt(cv, ci, xv, xi);   // keep the smaller (min)
                    cv = l ? xv : cv; ci = l ? xi : ci;
                }
                mv[k] = cv; mi[k] = ci;
            }
#pragma unroll
            for (int k = 0; k < TOPK_; k++) {
                tv[k] = mv[k]; ti[k] = mi[k];
                sv[tid * TOPK_ + k] = tv[k]; si[tid * TOPK_ + k] = ti[k];
            }
        }
        __syncthreads();
    }

    if (tid == 0) {
        unsigned int bit = 1u << (m & 31);
        int word = (m >= 32) ? 1 : 0;
        int d = 0;
#pragma unroll
        for (int k = 0; k < TOPK_; k++) {
            if (tv[k] > EPS_) atomicOr(&abits[2 * ((size_t)b * A_ + ti[k]) + word], bit);
            else d++;
        }
        if (d > 0) {
            // dropped top_k slots scatter onto anchor index 0, gated by in-box(anchor0)
            float s0 = strd[0];
            float ax = anc[0] * s0, ay = anc[1] * s0;
            if ((ax - g0) > EPS_ && (ay - g1) > EPS_ && (g2 - ax) > EPS_ && (g3 - ay) > EPS_)
                atomicOr(&abits[2 * ((size_t)b * A_) + word], bit);
        }
    }
}

// ------------------------------------------- K3: resolve multi-assignment per anchor
__global__ __launch_bounds__(256) void k_resolve(
    const unsigned int* __restrict__ abits,
    const float* __restrict__ pb, const float* __restrict__ anc,
    const float* __restrict__ strd, const float* __restrict__ gt,
    const float* __restrict__ mgt, const int* __restrict__ glab,
    int* __restrict__ tgti, int* __restrict__ tlab, unsigned char* __restrict__ fgm,
    int* __restrict__ blist, int* __restrict__ bcnt) {
    int idx = blockIdx.x * blockDim.x + threadIdx.x;
    if (idx >= B_ * A_) return;
    int b = idx / A_, a = idx % A_;
    unsigned int lo = abits[2 * idx], hi = abits[2 * idx + 1];
    int fg = __popc(lo) + __popc(hi);
    int tgt = 0;
    if (fg > 1) {
        // argmax over masked overlaps across all m (first max wins, like jnp.argmax)
        float bv = -1.f;
        for (int m = 0; m < M_; m++) {
            int bmi = b * M_ + m;
            float v = 0.f;
            if (mgt[bmi] > 0.f)
                v = ov_at(pb, anc, strd, gt[bmi * 4], gt[bmi * 4 + 1],
                          gt[bmi * 4 + 2], gt[bmi * 4 + 3], b, a);
            if (v > bv) { bv = v; tgt = m; }
        }
    } else if (fg == 1) {
        tgt = lo ? (__ffs(lo) - 1) : (32 + __ffs(hi) - 1);
    }
    tgti[idx] = tgt;
    tlab[idx] = max(glab[b * M_ + tgt], 0);
    fgm[idx] = (fg > 0) ? 1 : 0;
    if (fg > 0) { int p = atomicAdd(&bcnt[b], 1); blist[b * 512 + p] = a; }
}

// ------------------------------------------- K4: per-gt pos-max + per-anchor norm + tss
// One block per batch image. Also accumulates the sparse -x*t part of the BCE sum.
__global__ __launch_bounds__(256) void k_postnorm(
    const float* __restrict__ scores, const float* __restrict__ pb,
    const float* __restrict__ anc, const float* __restrict__ strd,
    const float* __restrict__ gt, const float* __restrict__ mgt,
    const int* __restrict__ glab, const int* __restrict__ tgti,
    const int* __restrict__ tlab,
    const int* __restrict__ blist, const int* __restrict__ bcnt,
    float* __restrict__ normv, float* __restrict__ acc) {
    int b = blockIdx.x;
    int tid = threadIdx.x;
    __shared__ int pa[M_], po[M_];       // float-as-int max (values >= 0)
    __shared__ float rp[M_];
    __shared__ float sal[512];
    for (int m = tid; m < M_; m += 256) { pa[m] = 0; po[m] = 0; }
    __syncthreads();
    int n = min(bcnt[b], 512);
    for (int i = tid; i < n; i += 256) {
        int a = blist[b * 512 + i];
        int m = tgti[b * A_ + a];
        int bmi = b * M_ + m;
        float ov = 0.f, al = 0.f;
        if (mgt[bmi] > 0.f) {
            ov = ov_at(pb, anc, strd, gt[bmi * 4], gt[bmi * 4 + 1],
                       gt[bmi * 4 + 2], gt[bmi * 4 + 3], b, a);
            if (ov > 0.f) {
                float sc = scores[((size_t)b * A_ + a) * NC_ + glab[bmi]];
                float bs = 1.f / (1.f + expf(-sc));
                float o2 = ov * ov;
                al = sqrtf(bs) * o2 * o2 * o2;
            }
        }
        sal[i] = al;
        atomicMax(&pa[m], __float_as_int(al));
        atomicMax(&po[m], __float_as_int(ov));
    }
    __syncthreads();
    for (int m = tid; m < M_; m += 256)
        rp[m] = __int_as_float(po[m]) / (__int_as_float(pa[m]) + EPS_);
    __syncthreads();
    float ts = 0.f, cs = 0.f;
    for (int i = tid; i < n; i += 256) {
        int a = blist[b * 512 + i];
        int m = tgti[b * A_ + a];
        float nv = sal[i] * rp[m];
        normv[b * A_ + a] = nv;
        ts += nv;                                               // tss contribution
        cs -= scores[((size_t)b * A_ + a) * NC_ + tlab[b * A_ + a]] * nv;  // -x*t
    }
    __shared__ float r1[256], r2[256];
    r1[tid] = ts; r2[tid] = cs;
    __syncthreads();
    for (int s = 128; s > 0; s >>= 1) {
        if (tid < s) { r1[tid] += r1[tid + s]; r2[tid] += r2[tid + s]; }
        __syncthreads();
    }
    if (tid == 0) { atomicAdd(&acc[0], r1[0]); atomicAdd(&acc[1], r2[0]); }
}

// ------------------------------------------- K5: streaming BCE (target-free part)
__global__ __launch_bounds__(256) void k_cls(const float4* __restrict__ s4,
                                             float* __restrict__ acc) {
    const int N4 = B_ * A_ * (NC_ / 4);
    float sum = 0.f;
    for (int i = blockIdx.x * blockDim.x + threadIdx.x; i < N4;
         i += gridDim.x * blockDim.x) {
        float4 x = s4[i];
        sum += fmaxf(x.x, 0.f) + __logf(1.f + __expf(-fabsf(x.x)));
        sum += fmaxf(x.y, 0.f) + __logf(1.f + __expf(-fabsf(x.y)));
        sum += fmaxf(x.z, 0.f) + __logf(1.f + __expf(-fabsf(x.z)));
        sum += fmaxf(x.w, 0.f) + __logf(1.f + __expf(-fabsf(x.w)));
    }
    __shared__ float sh[256];
    sh[threadIdx.x] = sum; __syncthreads();
    for (int s = 128; s > 0; s >>= 1) {
        if (threadIdx.x < s) sh[threadIdx.x] += sh[threadIdx.x + s];
        __syncthreads();
    }
    if (threadIdx.x == 0) atomicAdd(&acc[1], sh[0]);
}

// ------------------------------------------- K6: CIoU loss + DFL loss for fg anchors
__global__ __launch_bounds__(256) void k_boxdfl(
    const float* __restrict__ distri, const float* __restrict__ pb,
    const float* __restrict__ anc, const float* __restrict__ strd,
    const float* __restrict__ gt, const int* __restrict__ tgti,
    const unsigned char* __restrict__ fgm, const float* __restrict__ normv,
    float* __restrict__ acc) {
    int idx = blockIdx.x * blockDim.x + threadIdx.x;
    float liou = 0.f, ldfl = 0.f;
    if (idx < B_ * A_ && fgm[idx]) {
        int b = idx / A_, a = idx % A_;
        int m = tgti[idx];
        float w = normv[idx];
        float s = strd[a];
        const float* g = gt + ((size_t)b * M_ + m) * 4;
        float t0 = g[0] / s, t1 = g[1] / s, t2 = g[2] / s, t3 = g[3] / s;
        const float* p = pb + (size_t)idx * 4;
        float iou = ciou_f(p[0], p[1], p[2], p[3], t0, t1, t2, t3);
        liou = (1.f - iou) * w;
        float ax = anc[2 * a], ay = anc[2 * a + 1];
        float tg[4] = { ax - t0, ay - t1, t2 - ax, t3 - ay };
        const float* dd = distri + (size_t)idx * 64;
        float dfl = 0.f;
#pragma unroll
        for (int sd = 0; sd < 4; sd++) {
            float tvv = fminf(fmaxf(tg[sd], 0.f), 14.99f);
            int tl = (int)tvv;
            float wl = (float)(tl + 1) - tvv;
            float wr = 1.f - wl;
            const float* xx = dd + sd * 16;
            float mx = xx[0];
#pragma unroll
            for (int j = 1; j < 16; j++) mx = fmaxf(mx, xx[j]);
            float se = 0.f;
#pragma unroll
            for (int j = 0; j < 16; j++) se += __expf(xx[j] - mx);
            float lse = mx + __logf(se);
            dfl += (lse - xx[tl]) * wl + (lse - xx[tl + 1]) * wr;
        }
        ldfl = dfl * 0.25f * w;
    }
    __shared__ float s1[256], s2[256];
    s1[threadIdx.x] = liou; s2[threadIdx.x] = ldfl;
    __syncthreads();
    for (int s = 128; s > 0; s >>= 1) {
        if (threadIdx.x < s) {
            s1[threadIdx.x] += s1[threadIdx.x + s];
            s2[threadIdx.x] += s2[threadIdx.x + s];
        }
        __syncthreads();
    }
    if (threadIdx.x == 0) { atomicAdd(&acc[2], s1[0]); atomicAdd(&acc[3], s2[0]); }
}

// ------------------------------------------- K7: finalize
__global__ void k_final(const float* __restrict__ acc, float* __restrict__ out) {
    if (threadIdx.x == 0) {
        float tss = fmaxf(acc[0], 1.f);
        out[0] = acc[2] / tss * 7.5f;   // loss_iou * HYP_BOX
        out[1] = acc[1] / tss * 0.5f;   // loss_cls * HYP_CLS
        out[2] = acc[3] / tss * 1.5f;   // loss_dfl * HYP_DFL
    }
}

extern "C" void kernel_launch(void* const* d_in, const int* in_sizes, int n_in,
                              void* d_out, int out_size, void* d_ws, size_t ws_size,
                              hipStream_t stream) {
    const float* scores = (const float*)d_in[0];   // [B,A,NC]
    const float* distri = (const float*)d_in[1];   // [B,A,64]
    const float* anc    = (const float*)d_in[2];   // [A,2]  (grid units)
    const float* strd   = (const float*)d_in[3];   // [A,1]
    const float* gtb    = (const float*)d_in[4];   // [B,M,4] (pixels)
    const float* mgt    = (const float*)d_in[5];   // [B,M]
    const int*   glab   = (const int*)d_in[6];     // [B,M]
    float* out = (float*)d_out;

    // workspace layout (~10 MiB)
    float* pb    = (float*)d_ws;                            // B*A*4
    float* normv = pb + (size_t)B_ * A_ * 4;                // B*A (written for all fg anchors)
    float* acc   = normv + (size_t)B_ * A_;                 // 4      --+
    int*   bcnt  = (int*)(acc + 4);                         // 32       | zeroed region
    unsigned int* abits = (unsigned int*)(bcnt + 32);       // B*A*2  --+
    int*   blist = (int*)(abits + (size_t)B_ * A_ * 2);     // 32*512
    int*   tgti  = blist + 32 * 512;                        // B*A
    int*   tlab  = tgti + (size_t)B_ * A_;                  // B*A
    unsigned char* fgm = (unsigned char*)(tlab + (size_t)B_ * A_); // B*A

    // one contiguous memset: acc + bcnt + abits
    size_t zero_bytes = (4 + 32) * sizeof(int) + (size_t)B_ * A_ * 2 * sizeof(unsigned int);
    hipMemsetAsync(acc, 0, zero_bytes, stream);

    const int nBA = B_ * A_;   // 268800 = 1050 * 256

    k_predbox<<<1050, 256, 0, stream>>>(distri, anc, pb);
    k_aligntopk<<<B_ * M_, 256, 0, stream>>>(scores, pb, anc, strd, gtb, mgt, glab, abits);
    k_resolve<<<1050, 256, 0, stream>>>(abits, pb, anc, strd, gtb, mgt, glab,
                                        tgti, tlab, fgm, blist, bcnt);
    k_postnorm<<<B_, 256, 0, stream>>>(scores, pb, anc, strd, gtb, mgt, glab,
                                       tgti, tlab, blist, bcnt, normv, acc);
    k_cls<<<1280, 256, 0, stream>>>((const float4*)scores, acc);
    k_boxdfl<<<1050, 256, 0, stream>>>(distri, pb, anc, strd, gtb, tgti, fgm, normv, acc);
    k_final<<<1, 64, 0, stream>>>(acc, out);
    (void)in_sizes; (void)n_in; (void)out_size; (void)ws_size; (void)nBA;
}

// Round 4
// 385.906 us; speedup vs baseline: 1.5538x; 1.0107x over previous
//
#include <hip/hip_runtime.h>
#include <math.h>

#define B_    32
#define A_    8400
#define M_    40
#define NC_   80
#define TOPK_ 10
#define EPS_  1e-9f

// ---------------------------------------------------------------- CIoU
__device__ __forceinline__ float ciou_f(float b1x1, float b1y1, float b1x2, float b1y2,
                                        float b2x1, float b2y1, float b2x2, float b2y2) {
    const float eps = 1e-7f;
    float w1 = b1x2 - b1x1, h1 = b1y2 - b1y1 + eps;
    float w2 = b2x2 - b2x1, h2 = b2y2 - b2y1 + eps;
    float iw = fminf(b1x2, b2x2) - fmaxf(b1x1, b2x1);
    float ih = fminf(b1y2, b2y2) - fmaxf(b1y1, b2y1);
    float inter = fmaxf(iw, 0.f) * fmaxf(ih, 0.f);
    float uni = w1 * h1 + w2 * h2 - inter + eps;
    float iou = inter / uni;
    float cw = fmaxf(b1x2, b2x2) - fminf(b1x1, b2x1);
    float ch = fmaxf(b1y2, b2y2) - fminf(b1y1, b2y1);
    float c2 = cw * cw + ch * ch + eps;
    float dx = b2x1 + b2x2 - b1x1 - b1x2;
    float dy = b2y1 + b2y2 - b1y1 - b1y2;
    float rho2 = (dx * dx + dy * dy) * 0.25f;
    float da = atanf(w2 / h2) - atanf(w1 / h1);
    float v = 0.4052847345693511f * da * da;       // 4/pi^2
    float alpha = v / (v - iou + 1.f + eps);
    return iou - (rho2 / c2 + v * alpha);
}

// masked overlap at (b, gt-box g, anchor a); 0 if anchor center outside box
__device__ __forceinline__ float ov_at(const float* __restrict__ pb,
                                       const float* __restrict__ anc,
                                       const float* __restrict__ strd,
                                       float g0, float g1, float g2, float g3,
                                       int b, int a) {
    float s = strd[a];
    float ax = anc[2 * a] * s, ay = anc[2 * a + 1] * s;
    if (!((ax - g0) > EPS_ && (ay - g1) > EPS_ && (g2 - ax) > EPS_ && (g3 - ay) > EPS_))
        return 0.f;
    const float* p = pb + ((size_t)b * A_ + a) * 4;
    float c = ciou_f(g0, g1, g2, g3, p[0] * s, p[1] * s, p[2] * s, p[3] * s);
    return fmaxf(c, 0.f);
}

// (value desc, index asc) total order
__device__ __forceinline__ bool pair_gt(float v1, int i1, float v2, int i2) {
    return (v1 > v2) || (v1 == v2 && i1 < i2);
}

// ------------------------------------------- K1: DFL decode -> pred boxes (grid units)
__global__ __launch_bounds__(256) void k_predbox(const float* __restrict__ distri,
                                                 const float* __restrict__ anc,
                                                 float* __restrict__ pb) {
    int idx = blockIdx.x * blockDim.x + threadIdx.x;
    if (idx >= B_ * A_) return;
    int a = idx % A_;
    const float4* d4 = (const float4*)(distri + (size_t)idx * 64);
    float dist[4];
#pragma unroll
    for (int s = 0; s < 4; s++) {
        float4 q0 = d4[s * 4 + 0], q1 = d4[s * 4 + 1], q2 = d4[s * 4 + 2], q3 = d4[s * 4 + 3];
        float x[16] = { q0.x, q0.y, q0.z, q0.w, q1.x, q1.y, q1.z, q1.w,
                        q2.x, q2.y, q2.z, q2.w, q3.x, q3.y, q3.z, q3.w };
        float mx = x[0];
#pragma unroll
        for (int j = 1; j < 16; j++) mx = fmaxf(mx, x[j]);
        float se = 0.f, sd = 0.f;
#pragma unroll
        for (int j = 0; j < 16; j++) { float e = __expf(x[j] - mx); se += e; sd += e * (float)j; }
        dist[s] = sd / se;
    }
    float ax = anc[2 * a], ay = anc[2 * a + 1];
    float4* o = (float4*)(pb + (size_t)idx * 4);
    *o = make_float4(ax - dist[0], ay - dist[1], ax + dist[2], ay + dist[3]);
}

// ------------------------------------------- K2: fused align + single-pass top-10
__global__ __launch_bounds__(256) void k_aligntopk(
    const float* __restrict__ scores, const float* __restrict__ pb,
    const float* __restrict__ anc, const float* __restrict__ strd,
    const float* __restrict__ gt, const float* __restrict__ mgt,
    const int* __restrict__ glab, unsigned int* __restrict__ abits) {
    int bm = blockIdx.x;
    if (mgt[bm] <= 0.f) return;                 // row all-zero: no selection, no fallback
    int b = bm / M_, m = bm % M_;
    int lab = glab[bm];
    const float g0 = gt[bm * 4 + 0], g1 = gt[bm * 4 + 1];
    const float g2 = gt[bm * 4 + 2], g3 = gt[bm * 4 + 3];
    int tid = threadIdx.x;

    float tv[TOPK_]; int ti[TOPK_];
#pragma unroll
    for (int k = 0; k < TOPK_; k++) { tv[k] = -1.f; ti[k] = 0x7fffffff; }

    for (int a = tid; a < A_; a += 256) {
        float ov = ov_at(pb, anc, strd, g0, g1, g2, g3, b, a);
        float al = 0.f;
        if (ov > 0.f) {
            float sc = scores[((size_t)b * A_ + a) * NC_ + lab];
            float bs = 1.f / (1.f + __expf(-sc));
            float o2 = ov * ov;
            al = sqrtf(bs) * o2 * o2 * o2;      // bs^0.5 * ov^6
        }
        if (pair_gt(al, a, tv[TOPK_ - 1], ti[TOPK_ - 1])) {
            float cv = al; int ci = a;
#pragma unroll
            for (int k = 0; k < TOPK_; k++) {
                bool g = pair_gt(cv, ci, tv[k], ti[k]);
                float ovv = tv[k]; int oi = ti[k];
                tv[k] = g ? cv : ovv;  ti[k] = g ? ci : oi;
                cv    = g ? ovv : cv;  ci    = g ? oi : ci;
            }
        }
    }

    __shared__ float sv[256 * TOPK_];
    __shared__ int   si[256 * TOPK_];
#pragma unroll
    for (int k = 0; k < TOPK_; k++) { sv[tid * TOPK_ + k] = tv[k]; si[tid * TOPK_ + k] = ti[k]; }
    __syncthreads();

    for (int s = 128; s >= 1; s >>= 1) {
        if (tid < s) {
            int pbase = (tid + s) * TOPK_;
            float bv[TOPK_]; int bi[TOPK_];
#pragma unroll
            for (int k = 0; k < TOPK_; k++) { bv[k] = sv[pbase + k]; bi[k] = si[pbase + k]; }
            float mv[TOPK_]; int mi[TOPK_];
#pragma unroll
            for (int k = 0; k < TOPK_; k++) {
                bool g0b = pair_gt(tv[0], ti[0], bv[k], bi[k]);
                float cv = g0b ? tv[0] : bv[k];
                int   ci = g0b ? ti[0] : bi[k];
#pragma unroll
                for (int i = 1; i <= k; i++) {
                    bool g = pair_gt(tv[i], ti[i], bv[k - i], bi[k - i]);
                    float xv = g ? tv[i] : bv[k - i];
                    int   xi = g ? ti[i] : bi[k - i];
                    bool l = pair_gt(cv, ci, xv, xi);   // keep the smaller (min)
                    cv = l ? xv : cv; ci = l ? xi : ci;
                }
                mv[k] = cv; mi[k] = ci;
            }
#pragma unroll
            for (int k = 0; k < TOPK_; k++) {
                tv[k] = mv[k]; ti[k] = mi[k];
                sv[tid * TOPK_ + k] = tv[k]; si[tid * TOPK_ + k] = ti[k];
            }
        }
        __syncthreads();
    }

    if (tid == 0) {
        unsigned int bit = 1u << (m & 31);
        int word = (m >= 32) ? 1 : 0;
        int d = 0;
#pragma unroll
        for (int k = 0; k < TOPK_; k++) {
            if (tv[k] > EPS_) atomicOr(&abits[2 * ((size_t)b * A_ + ti[k]) + word], bit);
            else d++;
        }
        if (d > 0) {
            // dropped top_k slots scatter onto anchor index 0, gated by in-box(anchor0)
            float s0 = strd[0];
            float ax = anc[0] * s0, ay = anc[1] * s0;
            if ((ax - g0) > EPS_ && (ay - g1) > EPS_ && (g2 - ax) > EPS_ && (g3 - ay) > EPS_)
                atomicOr(&abits[2 * ((size_t)b * A_) + word], bit);
        }
    }
}

// ------------------------------------------- K3: resolve multi-assignment per anchor
// No global atomics: writes fgm always, tgti only for fg anchors.
__global__ __launch_bounds__(256) void k_resolve(
    const unsigned int* __restrict__ abits,
    const float* __restrict__ pb, const float* __restrict__ anc,
    const float* __restrict__ strd, const float* __restrict__ gt,
    const float* __restrict__ mgt,
    int* __restrict__ tgti, unsigned char* __restrict__ fgm) {
    int idx = blockIdx.x * blockDim.x + threadIdx.x;
    if (idx >= B_ * A_) return;
    int b = idx / A_, a = idx % A_;
    unsigned int lo = abits[2 * idx], hi = abits[2 * idx + 1];
    int fg = __popc(lo) + __popc(hi);
    fgm[idx] = (fg > 0) ? 1 : 0;
    if (fg == 0) return;
    int tgt;
    if (fg > 1) {
        // argmax over masked overlaps across all m (first max wins, like jnp.argmax)
        float bv = -1.f; tgt = 0;
        for (int m = 0; m < M_; m++) {
            int bmi = b * M_ + m;
            float v = 0.f;
            if (mgt[bmi] > 0.f)
                v = ov_at(pb, anc, strd, gt[bmi * 4], gt[bmi * 4 + 1],
                          gt[bmi * 4 + 2], gt[bmi * 4 + 3], b, a);
            if (v > bv) { bv = v; tgt = m; }
        }
    } else {
        tgt = lo ? (__ffs(lo) - 1) : (32 + __ffs(hi) - 1);
    }
    tgti[idx] = tgt;
}

// ------------------------------------------- K4: per-gt pos-max + per-anchor norm + tss
// One block per batch image; builds fg list in LDS by scanning fgm (no global atomics).
// Also accumulates the sparse -x*t part of the BCE sum.
__global__ __launch_bounds__(256) void k_postnorm(
    const float* __restrict__ scores, const float* __restrict__ pb,
    const float* __restrict__ anc, const float* __restrict__ strd,
    const float* __restrict__ gt, const float* __restrict__ mgt,
    const int* __restrict__ glab, const int* __restrict__ tgti,
    const unsigned char* __restrict__ fgm,
    float* __restrict__ normv, float* __restrict__ acc) {
    int b = blockIdx.x;
    int tid = threadIdx.x;
    __shared__ int pa[M_], po[M_];       // float-as-int max (values >= 0)
    __shared__ float rp[M_];
    __shared__ int   lcnt;
    __shared__ int   lpack[512];         // (m << 16) | a
    __shared__ float lal[512];
    if (tid == 0) lcnt = 0;
    for (int m = tid; m < M_; m += 256) { pa[m] = 0; po[m] = 0; }
    __syncthreads();
    for (int a = tid; a < A_; a += 256) {
        if (!fgm[b * A_ + a]) continue;
        int m = tgti[b * A_ + a];
        int bmi = b * M_ + m;
        float ov = 0.f, al = 0.f;
        if (mgt[bmi] > 0.f) {
            ov = ov_at(pb, anc, strd, gt[bmi * 4], gt[bmi * 4 + 1],
                       gt[bmi * 4 + 2], gt[bmi * 4 + 3], b, a);
            if (ov > 0.f) {
                float sc = scores[((size_t)b * A_ + a) * NC_ + glab[bmi]];
                float bs = 1.f / (1.f + __expf(-sc));
                float o2 = ov * ov;
                al = sqrtf(bs) * o2 * o2 * o2;
            }
        }
        int p = atomicAdd(&lcnt, 1);     // LDS atomic — cheap
        lpack[p] = (m << 16) | a;
        lal[p] = al;
        atomicMax(&pa[m], __float_as_int(al));
        atomicMax(&po[m], __float_as_int(ov));
    }
    __syncthreads();
    for (int m = tid; m < M_; m += 256)
        rp[m] = __int_as_float(po[m]) / (__int_as_float(pa[m]) + EPS_);
    __syncthreads();
    int n = lcnt;
    float ts = 0.f, cs = 0.f;
    for (int i = tid; i < n; i += 256) {
        int pk = lpack[i];
        int m = pk >> 16, a = pk & 0xffff;
        float nv = lal[i] * rp[m];
        normv[b * A_ + a] = nv;
        ts += nv;                                               // tss contribution
        int lab = max(glab[b * M_ + m], 0);
        cs -= scores[((size_t)b * A_ + a) * NC_ + lab] * nv;    // -x*t
    }
    __shared__ float r1[256], r2[256];
    r1[tid] = ts; r2[tid] = cs;
    __syncthreads();
    for (int s = 128; s > 0; s >>= 1) {
        if (tid < s) { r1[tid] += r1[tid + s]; r2[tid] += r2[tid + s]; }
        __syncthreads();
    }
    if (tid == 0) { atomicAdd(&acc[0], r1[0]); atomicAdd(&acc[1], r2[0]); }
}

// ------------------------------------------- K5: streaming BCE (target-free part)
__global__ __launch_bounds__(256) void k_cls(const float4* __restrict__ s4,
                                             float* __restrict__ acc) {
    const int N4 = B_ * A_ * (NC_ / 4);
    float sum = 0.f;
    for (int i = blockIdx.x * blockDim.x + threadIdx.x; i < N4;
         i += gridDim.x * blockDim.x) {
        float4 x = s4[i];
        sum += fmaxf(x.x, 0.f) + __logf(1.f + __expf(-fabsf(x.x)));
        sum += fmaxf(x.y, 0.f) + __logf(1.f + __expf(-fabsf(x.y)));
        sum += fmaxf(x.z, 0.f) + __logf(1.f + __expf(-fabsf(x.z)));
        sum += fmaxf(x.w, 0.f) + __logf(1.f + __expf(-fabsf(x.w)));
    }
    __shared__ float sh[256];
    sh[threadIdx.x] = sum; __syncthreads();
    for (int s = 128; s > 0; s >>= 1) {
        if (threadIdx.x < s) sh[threadIdx.x] += sh[threadIdx.x + s];
        __syncthreads();
    }
    if (threadIdx.x == 0) atomicAdd(&acc[1], sh[0]);
}

// ------------------------------------------- K6: CIoU loss + DFL loss for fg anchors
__global__ __launch_bounds__(256) void k_boxdfl(
    const float* __restrict__ distri, const float* __restrict__ pb,
    const float* __restrict__ anc, const float* __restrict__ strd,
    const float* __restrict__ gt, const int* __restrict__ tgti,
    const unsigned char* __restrict__ fgm, const float* __restrict__ normv,
    float* __restrict__ acc) {
    int idx = blockIdx.x * blockDim.x + threadIdx.x;
    float liou = 0.f, ldfl = 0.f;
    if (idx < B_ * A_ && fgm[idx]) {
        int b = idx / A_, a = idx % A_;
        int m = tgti[idx];
        float w = normv[idx];
        float s = strd[a];
        const float* g = gt + ((size_t)b * M_ + m) * 4;
        float t0 = g[0] / s, t1 = g[1] / s, t2 = g[2] / s, t3 = g[3] / s;
        const float* p = pb + (size_t)idx * 4;
        float iou = ciou_f(p[0], p[1], p[2], p[3], t0, t1, t2, t3);
        liou = (1.f - iou) * w;
        float ax = anc[2 * a], ay = anc[2 * a + 1];
        float tg[4] = { ax - t0, ay - t1, t2 - ax, t3 - ay };
        const float* dd = distri + (size_t)idx * 64;
        float dfl = 0.f;
#pragma unroll
        for (int sd = 0; sd < 4; sd++) {
            float tvv = fminf(fmaxf(tg[sd], 0.f), 14.99f);
            int tl = (int)tvv;
            float wl = (float)(tl + 1) - tvv;
            float wr = 1.f - wl;
            const float* xx = dd + sd * 16;
            float mx = xx[0];
#pragma unroll
            for (int j = 1; j < 16; j++) mx = fmaxf(mx, xx[j]);
            float se = 0.f;
#pragma unroll
            for (int j = 0; j < 16; j++) se += __expf(xx[j] - mx);
            float lse = mx + __logf(se);
            dfl += (lse - xx[tl]) * wl + (lse - xx[tl + 1]) * wr;
        }
        ldfl = dfl * 0.25f * w;
    }
    __shared__ float s1[256], s2[256];
    s1[threadIdx.x] = liou; s2[threadIdx.x] = ldfl;
    __syncthreads();
    for (int s = 128; s > 0; s >>= 1) {
        if (threadIdx.x < s) {
            s1[threadIdx.x] += s1[threadIdx.x + s];
            s2[threadIdx.x] += s2[threadIdx.x + s];
        }
        __syncthreads();
    }
    if (threadIdx.x == 0) { atomicAdd(&acc[2], s1[0]); atomicAdd(&acc[3], s2[0]); }
}

// ------------------------------------------- K7: finalize
__global__ void k_final(const float* __restrict__ acc, float* __restrict__ out) {
    if (threadIdx.x == 0) {
        float tss = fmaxf(acc[0], 1.f);
        out[0] = acc[2] / tss * 7.5f;   // loss_iou * HYP_BOX
        out[1] = acc[1] / tss * 0.5f;   // loss_cls * HYP_CLS
        out[2] = acc[3] / tss * 1.5f;   // loss_dfl * HYP_DFL
    }
}

extern "C" void kernel_launch(void* const* d_in, const int* in_sizes, int n_in,
                              void* d_out, int out_size, void* d_ws, size_t ws_size,
                              hipStream_t stream) {
    const float* scores = (const float*)d_in[0];   // [B,A,NC]
    const float* distri = (const float*)d_in[1];   // [B,A,64]
    const float* anc    = (const float*)d_in[2];   // [A,2]  (grid units)
    const float* strd   = (const float*)d_in[3];   // [A,1]
    const float* gtb    = (const float*)d_in[4];   // [B,M,4] (pixels)
    const float* mgt    = (const float*)d_in[5];   // [B,M]
    const int*   glab   = (const int*)d_in[6];     // [B,M]
    float* out = (float*)d_out;

    // workspace layout (~9 MiB)
    float* pb    = (float*)d_ws;                            // B*A*4
    float* normv = pb + (size_t)B_ * A_ * 4;                // B*A (written for fg anchors)
    float* acc   = normv + (size_t)B_ * A_;                 // 4      --+ zeroed
    unsigned int* abits = (unsigned int*)(acc + 4);         // B*A*2  --+ region
    int*   tgti  = (int*)(abits + (size_t)B_ * A_ * 2);     // B*A
    unsigned char* fgm = (unsigned char*)(tgti + (size_t)B_ * A_); // B*A

    // one contiguous memset: acc + abits
    size_t zero_bytes = 4 * sizeof(float) + (size_t)B_ * A_ * 2 * sizeof(unsigned int);
    hipMemsetAsync(acc, 0, zero_bytes, stream);

    k_predbox<<<1050, 256, 0, stream>>>(distri, anc, pb);
    k_aligntopk<<<B_ * M_, 256, 0, stream>>>(scores, pb, anc, strd, gtb, mgt, glab, abits);
    k_resolve<<<1050, 256, 0, stream>>>(abits, pb, anc, strd, gtb, mgt, tgti, fgm);
    k_postnorm<<<B_, 256, 0, stream>>>(scores, pb, anc, strd, gtb, mgt, glab,
                                       tgti, fgm, normv, acc);
    k_cls<<<1280, 256, 0, stream>>>((const float4*)scores, acc);
    k_boxdfl<<<1050, 256, 0, stream>>>(distri, pb, anc, strd, gtb, tgti, fgm, normv, acc);
    k_final<<<1, 64, 0, stream>>>(acc, out);
    (void)in_sizes; (void)n_in; (void)out_size; (void)ws_size;
}

// Round 5
// 335.508 us; speedup vs baseline: 1.7872x; 1.1502x over previous
//
#include <hip/hip_runtime.h>
#include <math.h>

#define B_    32
#define A_    8400
#define M_    40
#define NC_   80
#define TOPK_ 10
#define EPS_  1e-9f

// ---------------------------------------------------------------- CIoU
__device__ __forceinline__ float ciou_f(float b1x1, float b1y1, float b1x2, float b1y2,
                                        float b2x1, float b2y1, float b2x2, float b2y2) {
    const float eps = 1e-7f;
    float w1 = b1x2 - b1x1, h1 = b1y2 - b1y1 + eps;
    float w2 = b2x2 - b2x1, h2 = b2y2 - b2y1 + eps;
    float iw = fminf(b1x2, b2x2) - fmaxf(b1x1, b2x1);
    float ih = fminf(b1y2, b2y2) - fmaxf(b1y1, b2y1);
    float inter = fmaxf(iw, 0.f) * fmaxf(ih, 0.f);
    float uni = w1 * h1 + w2 * h2 - inter + eps;
    float iou = inter / uni;
    float cw = fmaxf(b1x2, b2x2) - fminf(b1x1, b2x1);
    float ch = fmaxf(b1y2, b2y2) - fminf(b1y1, b2y1);
    float c2 = cw * cw + ch * ch + eps;
    float dx = b2x1 + b2x2 - b1x1 - b1x2;
    float dy = b2y1 + b2y2 - b1y1 - b1y2;
    float rho2 = (dx * dx + dy * dy) * 0.25f;
    float da = atanf(w2 / h2) - atanf(w1 / h1);
    float v = 0.4052847345693511f * da * da;       // 4/pi^2
    float alpha = v / (v - iou + 1.f + eps);
    return iou - (rho2 / c2 + v * alpha);
}

// masked overlap at (b, gt-box g, anchor a); 0 if anchor center outside box
__device__ __forceinline__ float ov_at(const float* __restrict__ pb,
                                       const float* __restrict__ anc,
                                       const float* __restrict__ strd,
                                       float g0, float g1, float g2, float g3,
                                       int b, int a) {
    float s = strd[a];
    float ax = anc[2 * a] * s, ay = anc[2 * a + 1] * s;
    if (!((ax - g0) > EPS_ && (ay - g1) > EPS_ && (g2 - ax) > EPS_ && (g3 - ay) > EPS_))
        return 0.f;
    const float* p = pb + ((size_t)b * A_ + a) * 4;
    float c = ciou_f(g0, g1, g2, g3, p[0] * s, p[1] * s, p[2] * s, p[3] * s);
    return fmaxf(c, 0.f);
}

__device__ __forceinline__ unsigned long long shflxor_u64(unsigned long long v, int m) {
    int lo = __shfl_xor((int)(unsigned)(v & 0xffffffffull), m, 64);
    int hi = __shfl_xor((int)(unsigned)(v >> 32), m, 64);
    return ((unsigned long long)(unsigned)hi << 32) | (unsigned)lo;
}

// ------------------------------------------- K1: fused DFL-decode + streaming BCE
__global__ __launch_bounds__(256) void k_stream(const float* __restrict__ distri,
                                                const float* __restrict__ anc,
                                                const float4* __restrict__ s4,
                                                float* __restrict__ pb,
                                                float* __restrict__ acc) {
    const int tid0 = blockIdx.x * blockDim.x + threadIdx.x;
    const int nthr = gridDim.x * blockDim.x;
    // ---- part A: pred boxes
    for (int idx = tid0; idx < B_ * A_; idx += nthr) {
        int a = idx % A_;
        const float4* d4 = (const float4*)(distri + (size_t)idx * 64);
        float dist[4];
#pragma unroll
        for (int s = 0; s < 4; s++) {
            float4 q0 = d4[s * 4 + 0], q1 = d4[s * 4 + 1], q2 = d4[s * 4 + 2], q3 = d4[s * 4 + 3];
            float x[16] = { q0.x, q0.y, q0.z, q0.w, q1.x, q1.y, q1.z, q1.w,
                            q2.x, q2.y, q2.z, q2.w, q3.x, q3.y, q3.z, q3.w };
            float mx = x[0];
#pragma unroll
            for (int j = 1; j < 16; j++) mx = fmaxf(mx, x[j]);
            float se = 0.f, sd = 0.f;
#pragma unroll
            for (int j = 0; j < 16; j++) { float e = __expf(x[j] - mx); se += e; sd += e * (float)j; }
            dist[s] = sd / se;
        }
        float ax = anc[2 * a], ay = anc[2 * a + 1];
        float4* o = (float4*)(pb + (size_t)idx * 4);
        *o = make_float4(ax - dist[0], ay - dist[1], ax + dist[2], ay + dist[3]);
    }
    // ---- part B: BCE target-free part over all logits
    const int N4 = B_ * A_ * (NC_ / 4);
    float sum = 0.f;
    for (int i = tid0; i < N4; i += nthr) {
        float4 x = s4[i];
        sum += fmaxf(x.x, 0.f) + __logf(1.f + __expf(-fabsf(x.x)));
        sum += fmaxf(x.y, 0.f) + __logf(1.f + __expf(-fabsf(x.y)));
        sum += fmaxf(x.z, 0.f) + __logf(1.f + __expf(-fabsf(x.z)));
        sum += fmaxf(x.w, 0.f) + __logf(1.f + __expf(-fabsf(x.w)));
    }
    __shared__ float sh[256];
    sh[threadIdx.x] = sum; __syncthreads();
    for (int s = 128; s > 0; s >>= 1) {
        if (threadIdx.x < s) sh[threadIdx.x] += sh[threadIdx.x + s];
        __syncthreads();
    }
    if (threadIdx.x == 0) atomicAdd(&acc[1], sh[0]);
}

// ------------------------------------------- K2: rect-scan align + wave top-10
// One 64-thread wave per (b,m). Candidate anchors enumerated from the closed-form
// in-box rectangle per pyramid level (±1 margin, exact float test inside).
__global__ __launch_bounds__(64) void k_aligntopk(
    const float* __restrict__ scores, const float* __restrict__ pb,
    const float* __restrict__ gt, const float* __restrict__ mgt,
    const int* __restrict__ glab, unsigned int* __restrict__ abits) {
    int bm = blockIdx.x;
    if (mgt[bm] <= 0.f) return;                 // row all-zero: no selection, no fallback
    int b = bm / M_, m = bm % M_;
    int lab = glab[bm];
    const float g0 = gt[bm * 4 + 0], g1 = gt[bm * 4 + 1];
    const float g2 = gt[bm * 4 + 2], g3 = gt[bm * 4 + 3];
    int lane = threadIdx.x;

    // per-level rects
    const int   Wl[3]  = { 80, 40, 20 };
    const int   Bs[3]  = { 0, 6400, 8000 };
    const float Sl[3]  = { 8.f, 16.f, 32.f };
    int jlo[3], ilo[3], rw[3], cnt[3];
#pragma unroll
    for (int l = 0; l < 3; l++) {
        float s = Sl[l]; int W = Wl[l];
        int jl = max(0, (int)floorf(g0 / s - 0.5f) - 1);
        int jh = min(W - 1, (int)ceilf(g2 / s - 0.5f) + 1);
        int il = max(0, (int)floorf(g1 / s - 0.5f) - 1);
        int ih = min(W - 1, (int)ceilf(g3 / s - 0.5f) + 1);
        int w = jh - jl + 1, h = ih - il + 1;
        jlo[l] = jl; ilo[l] = il; rw[l] = max(w, 0);
        cnt[l] = (w > 0 && h > 0) ? w * h : 0;
    }
    int c01 = cnt[0] + cnt[1];
    int tot = c01 + cnt[2];

    // per-lane sorted (desc) top-10, packed u64 = (f32bits(val)<<32) | ~idx
    unsigned long long t[TOPK_];
#pragma unroll
    for (int k = 0; k < TOPK_; k++) t[k] = 0ull;

    for (int c = lane; c < tot; c += 64) {
        int l = (c < cnt[0]) ? 0 : ((c < c01) ? 1 : 2);
        int r = c - ((l == 0) ? 0 : ((l == 1) ? cnt[0] : c01));
        int w = rw[l];
        int di = r / w, dj = r - di * w;
        int i = ilo[l] + di, j = jlo[l] + dj;
        float s = Sl[l];
        float ax = ((float)j + 0.5f) * s;      // exact, == anc[2a]*strd[a]
        float ay = ((float)i + 0.5f) * s;
        if (!((ax - g0) > EPS_ && (ay - g1) > EPS_ && (g2 - ax) > EPS_ && (g3 - ay) > EPS_))
            continue;
        int a = Bs[l] + i * Wl[l] + j;
        const float4 p = *(const float4*)(pb + ((size_t)b * A_ + a) * 4);
        float ci = ciou_f(g0, g1, g2, g3, p.x * s, p.y * s, p.z * s, p.w * s);
        float ov = fmaxf(ci, 0.f);
        float al = 0.f;
        if (ov > 0.f) {
            float sc = scores[((size_t)b * A_ + a) * NC_ + lab];
            float bs = 1.f / (1.f + __expf(-sc));
            float o2 = ov * ov;
            al = sqrtf(bs) * o2 * o2 * o2;     // bs^0.5 * ov^6
        }
        unsigned long long pkd = ((unsigned long long)__float_as_uint(al) << 32)
                                 | (unsigned)(~(unsigned)a);
        if (pkd > t[TOPK_ - 1]) {
            unsigned long long cv = pkd;
#pragma unroll
            for (int k = 0; k < TOPK_; k++) {
                bool g = cv > t[k];
                unsigned long long o = t[k];
                t[k] = g ? cv : o;
                cv   = g ? o : cv;
            }
        }
    }

    // 10 rounds of wave-argmax with winner removal; lane k keeps winner k
    unsigned long long mysel = 0ull;
#pragma unroll
    for (int k = 0; k < TOPK_; k++) {
        unsigned long long w = t[0];
#pragma unroll
        for (int off = 32; off >= 1; off >>= 1) {
            unsigned long long o = shflxor_u64(w, off);
            if (o > w) w = o;
        }
        if (lane == k) mysel = w;
        if (w != 0ull && t[0] == w) {
#pragma unroll
            for (int q = 0; q < TOPK_ - 1; q++) t[q] = t[q + 1];
            t[TOPK_ - 1] = 0ull;
        }
    }

    float sval = __uint_as_float((unsigned)(mysel >> 32));
    int   sidx = (int)(~(unsigned)mysel);
    unsigned int bit = 1u << (m & 31);
    int word = (m >= 32) ? 1 : 0;
    bool keep = (lane < TOPK_) && (sval > EPS_);
    if (keep) atomicOr(&abits[2 * ((size_t)b * A_ + sidx) + word], bit);
    unsigned long long kb = __ballot(keep);
    if (lane == 0 && __popcll(kb) < TOPK_) {
        // dropped top_k slots scatter onto anchor index 0, gated by in-box(anchor0)
        float ax = 4.f, ay = 4.f;               // (0.5)*8
        if ((ax - g0) > EPS_ && (ay - g1) > EPS_ && (g2 - ax) > EPS_ && (g3 - ay) > EPS_)
            atomicOr(&abits[2 * ((size_t)b * A_) + word], bit);
    }
}

// ------------------------------------------- K3: resolve multi-assignment per anchor
__global__ __launch_bounds__(256) void k_resolve(
    const unsigned int* __restrict__ abits,
    const float* __restrict__ pb, const float* __restrict__ anc,
    const float* __restrict__ strd, const float* __restrict__ gt,
    const float* __restrict__ mgt,
    int* __restrict__ tgti, unsigned char* __restrict__ fgm) {
    int idx = blockIdx.x * blockDim.x + threadIdx.x;
    if (idx >= B_ * A_) return;
    int b = idx / A_, a = idx % A_;
    unsigned int lo = abits[2 * idx], hi = abits[2 * idx + 1];
    int fg = __popc(lo) + __popc(hi);
    fgm[idx] = (fg > 0) ? 1 : 0;
    if (fg == 0) return;
    int tgt;
    if (fg > 1) {
        // argmax over masked overlaps across all m (first max wins, like jnp.argmax)
        float bv = -1.f; tgt = 0;
        for (int m = 0; m < M_; m++) {
            int bmi = b * M_ + m;
            float v = 0.f;
            if (mgt[bmi] > 0.f)
                v = ov_at(pb, anc, strd, gt[bmi * 4], gt[bmi * 4 + 1],
                          gt[bmi * 4 + 2], gt[bmi * 4 + 3], b, a);
            if (v > bv) { bv = v; tgt = m; }
        }
    } else {
        tgt = lo ? (__ffs(lo) - 1) : (32 + __ffs(hi) - 1);
    }
    tgti[idx] = tgt;
}

// ------------------------------------------- K4: per-gt pos-max + per-anchor norm + tss
__global__ __launch_bounds__(256) void k_postnorm(
    const float* __restrict__ scores, const float* __restrict__ pb,
    const float* __restrict__ anc, const float* __restrict__ strd,
    const float* __restrict__ gt, const float* __restrict__ mgt,
    const int* __restrict__ glab, const int* __restrict__ tgti,
    const unsigned char* __restrict__ fgm,
    float* __restrict__ normv, float* __restrict__ acc) {
    int b = blockIdx.x;
    int tid = threadIdx.x;
    __shared__ int pa[M_], po[M_];       // float-as-int max (values >= 0)
    __shared__ float rp[M_];
    __shared__ int   lcnt;
    __shared__ int   lpack[512];         // (m << 16) | a
    __shared__ float lal[512];
    if (tid == 0) lcnt = 0;
    for (int m = tid; m < M_; m += 256) { pa[m] = 0; po[m] = 0; }
    __syncthreads();
    for (int a = tid; a < A_; a += 256) {
        if (!fgm[b * A_ + a]) continue;
        int m = tgti[b * A_ + a];
        int bmi = b * M_ + m;
        float ov = 0.f, al = 0.f;
        if (mgt[bmi] > 0.f) {
            ov = ov_at(pb, anc, strd, gt[bmi * 4], gt[bmi * 4 + 1],
                       gt[bmi * 4 + 2], gt[bmi * 4 + 3], b, a);
            if (ov > 0.f) {
                float sc = scores[((size_t)b * A_ + a) * NC_ + glab[bmi]];
                float bs = 1.f / (1.f + __expf(-sc));
                float o2 = ov * ov;
                al = sqrtf(bs) * o2 * o2 * o2;
            }
        }
        int p = atomicAdd(&lcnt, 1);     // LDS atomic — cheap
        lpack[p] = (m << 16) | a;
        lal[p] = al;
        atomicMax(&pa[m], __float_as_int(al));
        atomicMax(&po[m], __float_as_int(ov));
    }
    __syncthreads();
    for (int m = tid; m < M_; m += 256)
        rp[m] = __int_as_float(po[m]) / (__int_as_float(pa[m]) + EPS_);
    __syncthreads();
    int n = lcnt;
    float ts = 0.f, cs = 0.f;
    for (int i = tid; i < n; i += 256) {
        int pk = lpack[i];
        int m = pk >> 16, a = pk & 0xffff;
        float nv = lal[i] * rp[m];
        normv[b * A_ + a] = nv;
        ts += nv;                                               // tss contribution
        int lab = max(glab[b * M_ + m], 0);
        cs -= scores[((size_t)b * A_ + a) * NC_ + lab] * nv;    // -x*t
    }
    __shared__ float r1[256], r2[256];
    r1[tid] = ts; r2[tid] = cs;
    __syncthreads();
    for (int s = 128; s > 0; s >>= 1) {
        if (tid < s) { r1[tid] += r1[tid + s]; r2[tid] += r2[tid + s]; }
        __syncthreads();
    }
    if (tid == 0) { atomicAdd(&acc[0], r1[0]); atomicAdd(&acc[1], r2[0]); }
}

// ------------------------------------------- K5: CIoU loss + DFL loss for fg anchors
__global__ __launch_bounds__(256) void k_boxdfl(
    const float* __restrict__ distri, const float* __restrict__ pb,
    const float* __restrict__ anc, const float* __restrict__ strd,
    const float* __restrict__ gt, const int* __restrict__ tgti,
    const unsigned char* __restrict__ fgm, const float* __restrict__ normv,
    float* __restrict__ acc) {
    int idx = blockIdx.x * blockDim.x + threadIdx.x;
    float liou = 0.f, ldfl = 0.f;
    if (idx < B_ * A_ && fgm[idx]) {
        int b = idx / A_, a = idx % A_;
        int m = tgti[idx];
        float w = normv[idx];
        float s = strd[a];
        const float* g = gt + ((size_t)b * M_ + m) * 4;
        float t0 = g[0] / s, t1 = g[1] / s, t2 = g[2] / s, t3 = g[3] / s;
        const float* p = pb + (size_t)idx * 4;
        float iou = ciou_f(p[0], p[1], p[2], p[3], t0, t1, t2, t3);
        liou = (1.f - iou) * w;
        float ax = anc[2 * a], ay = anc[2 * a + 1];
        float tg[4] = { ax - t0, ay - t1, t2 - ax, t3 - ay };
        const float* dd = distri + (size_t)idx * 64;
        float dfl = 0.f;
#pragma unroll
        for (int sd = 0; sd < 4; sd++) {
            float tvv = fminf(fmaxf(tg[sd], 0.f), 14.99f);
            int tl = (int)tvv;
            float wl = (float)(tl + 1) - tvv;
            float wr = 1.f - wl;
            const float* xx = dd + sd * 16;
            float mx = xx[0];
#pragma unroll
            for (int j = 1; j < 16; j++) mx = fmaxf(mx, xx[j]);
            float se = 0.f;
#pragma unroll
            for (int j = 0; j < 16; j++) se += __expf(xx[j] - mx);
            float lse = mx + __logf(se);
            dfl += (lse - xx[tl]) * wl + (lse - xx[tl + 1]) * wr;
        }
        ldfl = dfl * 0.25f * w;
    }
    __shared__ float s1[256], s2[256];
    s1[threadIdx.x] = liou; s2[threadIdx.x] = ldfl;
    __syncthreads();
    for (int s = 128; s > 0; s >>= 1) {
        if (threadIdx.x < s) {
            s1[threadIdx.x] += s1[threadIdx.x + s];
            s2[threadIdx.x] += s2[threadIdx.x + s];
        }
        __syncthreads();
    }
    if (threadIdx.x == 0) { atomicAdd(&acc[2], s1[0]); atomicAdd(&acc[3], s2[0]); }
}

// ------------------------------------------- K6: finalize
__global__ void k_final(const float* __restrict__ acc, float* __restrict__ out) {
    if (threadIdx.x == 0) {
        float tss = fmaxf(acc[0], 1.f);
        out[0] = acc[2] / tss * 7.5f;   // loss_iou * HYP_BOX
        out[1] = acc[1] / tss * 0.5f;   // loss_cls * HYP_CLS
        out[2] = acc[3] / tss * 1.5f;   // loss_dfl * HYP_DFL
    }
}

extern "C" void kernel_launch(void* const* d_in, const int* in_sizes, int n_in,
                              void* d_out, int out_size, void* d_ws, size_t ws_size,
                              hipStream_t stream) {
    const float* scores = (const float*)d_in[0];   // [B,A,NC]
    const float* distri = (const float*)d_in[1];   // [B,A,64]
    const float* anc    = (const float*)d_in[2];   // [A,2]  (grid units)
    const float* strd   = (const float*)d_in[3];   // [A,1]
    const float* gtb    = (const float*)d_in[4];   // [B,M,4] (pixels)
    const float* mgt    = (const float*)d_in[5];   // [B,M]
    const int*   glab   = (const int*)d_in[6];     // [B,M]
    float* out = (float*)d_out;

    // workspace layout (~9 MiB)
    float* pb    = (float*)d_ws;                            // B*A*4
    float* normv = pb + (size_t)B_ * A_ * 4;                // B*A (written for fg anchors)
    float* acc   = normv + (size_t)B_ * A_;                 // 4      --+ zeroed
    unsigned int* abits = (unsigned int*)(acc + 4);         // B*A*2  --+ region
    int*   tgti  = (int*)(abits + (size_t)B_ * A_ * 2);     // B*A
    unsigned char* fgm = (unsigned char*)(tgti + (size_t)B_ * A_); // B*A

    // one contiguous memset: acc + abits
    size_t zero_bytes = 4 * sizeof(float) + (size_t)B_ * A_ * 2 * sizeof(unsigned int);
    hipMemsetAsync(acc, 0, zero_bytes, stream);

    k_stream<<<1024, 256, 0, stream>>>(distri, anc, (const float4*)scores, pb, acc);
    k_aligntopk<<<B_ * M_, 64, 0, stream>>>(scores, pb, gtb, mgt, glab, abits);
    k_resolve<<<1050, 256, 0, stream>>>(abits, pb, anc, strd, gtb, mgt, tgti, fgm);
    k_postnorm<<<B_, 256, 0, stream>>>(scores, pb, anc, strd, gtb, mgt, glab,
                                       tgti, fgm, normv, acc);
    k_boxdfl<<<1050, 256, 0, stream>>>(distri, pb, anc, strd, gtb, tgti, fgm, normv, acc);
    k_final<<<1, 64, 0, stream>>>(acc, out);
    (void)in_sizes; (void)n_in; (void)out_size; (void)ws_size;
}

// Round 6
// 293.564 us; speedup vs baseline: 2.0426x; 1.1429x over previous
//
#include <hip/hip_runtime.h>
#include <math.h>

#define B_    32
#define A_    8400
#define M_    40
#define NC_   80
#define TOPK_ 10
#define EPS_  1e-9f

// ---------------------------------------------------------------- CIoU
__device__ __forceinline__ float ciou_f(float b1x1, float b1y1, float b1x2, float b1y2,
                                        float b2x1, float b2y1, float b2x2, float b2y2) {
    const float eps = 1e-7f;
    float w1 = b1x2 - b1x1, h1 = b1y2 - b1y1 + eps;
    float w2 = b2x2 - b2x1, h2 = b2y2 - b2y1 + eps;
    float iw = fminf(b1x2, b2x2) - fmaxf(b1x1, b2x1);
    float ih = fminf(b1y2, b2y2) - fmaxf(b1y1, b2y1);
    float inter = fmaxf(iw, 0.f) * fmaxf(ih, 0.f);
    float uni = w1 * h1 + w2 * h2 - inter + eps;
    float iou = inter / uni;
    float cw = fmaxf(b1x2, b2x2) - fminf(b1x1, b2x1);
    float ch = fmaxf(b1y2, b2y2) - fminf(b1y1, b2y1);
    float c2 = cw * cw + ch * ch + eps;
    float dx = b2x1 + b2x2 - b1x1 - b1x2;
    float dy = b2y1 + b2y2 - b1y1 - b1y2;
    float rho2 = (dx * dx + dy * dy) * 0.25f;
    float da = atanf(w2 / h2) - atanf(w1 / h1);
    float v = 0.4052847345693511f * da * da;       // 4/pi^2
    float alpha = v / (v - iou + 1.f + eps);
    return iou - (rho2 / c2 + v * alpha);
}

// closed-form anchor: grid-unit center (ax,ay) and stride s for anchor index a
__device__ __forceinline__ void anchor_of(int a, float& ax, float& ay, float& s) {
    if (a < 6400)      { s = 8.f;  int r = a;        ax = (float)(r % 80) + 0.5f; ay = (float)(r / 80) + 0.5f; }
    else if (a < 8000) { s = 16.f; int r = a - 6400; ax = (float)(r % 40) + 0.5f; ay = (float)(r / 40) + 0.5f; }
    else               { s = 32.f; int r = a - 8000; ax = (float)(r % 20) + 0.5f; ay = (float)(r / 20) + 0.5f; }
}

// masked overlap at (b, gt-box g, anchor a); 0 if anchor center outside box
__device__ __forceinline__ float ov_at2(const float* __restrict__ pb,
                                        float g0, float g1, float g2, float g3,
                                        int b, int a) {
    float ax, ay, s; anchor_of(a, ax, ay, s);
    float axp = ax * s, ayp = ay * s;
    if (!((axp - g0) > EPS_ && (ayp - g1) > EPS_ && (g2 - axp) > EPS_ && (g3 - ayp) > EPS_))
        return 0.f;
    const float4 p = *(const float4*)(pb + ((size_t)b * A_ + a) * 4);
    float c = ciou_f(g0, g1, g2, g3, p.x * s, p.y * s, p.z * s, p.w * s);
    return fmaxf(c, 0.f);
}

__device__ __forceinline__ unsigned long long shflxor_u64(unsigned long long v, int m) {
    int lo = __shfl_xor((int)(unsigned)(v & 0xffffffffull), m, 64);
    int hi = __shfl_xor((int)(unsigned)(v >> 32), m, 64);
    return ((unsigned long long)(unsigned)hi << 32) | (unsigned)lo;
}

// ------------------------------------------- K1: fused DFL-decode + streaming BCE
// Part A: one float4 per lane (coalesced); each 4-lane quad does the 16-bin softmax.
__global__ __launch_bounds__(256) void k_stream(const float4* __restrict__ d4,
                                                const float4* __restrict__ s4,
                                                float* __restrict__ pb,
                                                float* __restrict__ acc) {
    const int tid0 = blockIdx.x * blockDim.x + threadIdx.x;
    const int nthr = gridDim.x * blockDim.x;           // multiple of 16
    // ---- part A: pred boxes (NF4 = B*A*16 float4s, divisible by 64)
    const int NF4 = B_ * A_ * 16;
    for (int f = tid0; f < NF4; f += nthr) {
        float4 v = d4[f];
        int q = f & 3;                                 // quad slot == lane&3
        float mx = fmaxf(fmaxf(v.x, v.y), fmaxf(v.z, v.w));
        mx = fmaxf(mx, __shfl_xor(mx, 1, 64));
        mx = fmaxf(mx, __shfl_xor(mx, 2, 64));
        float e0 = __expf(v.x - mx), e1 = __expf(v.y - mx);
        float e2 = __expf(v.z - mx), e3 = __expf(v.w - mx);
        float se = e0 + e1 + e2 + e3;
        float sd = e1 + 2.f * e2 + 3.f * e3 + (float)(4 * q) * se;
        se += __shfl_xor(se, 1, 64); se += __shfl_xor(se, 2, 64);
        sd += __shfl_xor(sd, 1, 64); sd += __shfl_xor(sd, 2, 64);
        float dist = sd / se;                          // same in all 4 lanes of quad
        float d1 = __shfl_down(dist, 4, 64);
        float d2 = __shfl_down(dist, 8, 64);
        float d3 = __shfl_down(dist, 12, 64);
        if ((f & 15) == 0) {
            int aidx = f >> 4;                         // global b*A + a
            int a = aidx % A_;
            float ax, ay, s; anchor_of(a, ax, ay, s);
            ((float4*)pb)[aidx] = make_float4(ax - dist, ay - d1, ax + d2, ay + d3);
        }
    }
    // ---- part B: BCE target-free part over all logits
    const int N4 = B_ * A_ * (NC_ / 4);
    float sum = 0.f;
    for (int i = tid0; i < N4; i += nthr) {
        float4 x = s4[i];
        sum += fmaxf(x.x, 0.f) + __logf(1.f + __expf(-fabsf(x.x)));
        sum += fmaxf(x.y, 0.f) + __logf(1.f + __expf(-fabsf(x.y)));
        sum += fmaxf(x.z, 0.f) + __logf(1.f + __expf(-fabsf(x.z)));
        sum += fmaxf(x.w, 0.f) + __logf(1.f + __expf(-fabsf(x.w)));
    }
    __shared__ float sh[256];
    sh[threadIdx.x] = sum; __syncthreads();
    for (int s = 128; s > 0; s >>= 1) {
        if (threadIdx.x < s) sh[threadIdx.x] += sh[threadIdx.x + s];
        __syncthreads();
    }
    if (threadIdx.x == 0) atomicAdd(&acc[1], sh[0]);
}

// ------------------------------------------- K2: rect-scan align + wave top-10
__global__ __launch_bounds__(64) void k_aligntopk(
    const float* __restrict__ scores, const float* __restrict__ pb,
    const float* __restrict__ gt, const float* __restrict__ mgt,
    const int* __restrict__ glab, unsigned int* __restrict__ abits) {
    int bm = blockIdx.x;
    if (mgt[bm] <= 0.f) return;                 // row all-zero: no selection, no fallback
    int b = bm / M_, m = bm % M_;
    int lab = glab[bm];
    const float g0 = gt[bm * 4 + 0], g1 = gt[bm * 4 + 1];
    const float g2 = gt[bm * 4 + 2], g3 = gt[bm * 4 + 3];
    int lane = threadIdx.x;

    const int   Wl[3]  = { 80, 40, 20 };
    const int   Bs[3]  = { 0, 6400, 8000 };
    const float Sl[3]  = { 8.f, 16.f, 32.f };
    int jlo[3], ilo[3], rw[3], cnt[3];
#pragma unroll
    for (int l = 0; l < 3; l++) {
        float s = Sl[l]; int W = Wl[l];
        int jl = max(0, (int)floorf(g0 / s - 0.5f) - 1);
        int jh = min(W - 1, (int)ceilf(g2 / s - 0.5f) + 1);
        int il = max(0, (int)floorf(g1 / s - 0.5f) - 1);
        int ih = min(W - 1, (int)ceilf(g3 / s - 0.5f) + 1);
        int w = jh - jl + 1, h = ih - il + 1;
        jlo[l] = jl; ilo[l] = il; rw[l] = max(w, 0);
        cnt[l] = (w > 0 && h > 0) ? w * h : 0;
    }
    int c01 = cnt[0] + cnt[1];
    int tot = c01 + cnt[2];

    unsigned long long t[TOPK_];
#pragma unroll
    for (int k = 0; k < TOPK_; k++) t[k] = 0ull;

    for (int c = lane; c < tot; c += 64) {
        int l = (c < cnt[0]) ? 0 : ((c < c01) ? 1 : 2);
        int r = c - ((l == 0) ? 0 : ((l == 1) ? cnt[0] : c01));
        int w = rw[l];
        int di = r / w, dj = r - di * w;
        int i = ilo[l] + di, j = jlo[l] + dj;
        float s = Sl[l];
        float ax = ((float)j + 0.5f) * s;
        float ay = ((float)i + 0.5f) * s;
        if (!((ax - g0) > EPS_ && (ay - g1) > EPS_ && (g2 - ax) > EPS_ && (g3 - ay) > EPS_))
            continue;
        int a = Bs[l] + i * Wl[l] + j;
        const float4 p = *(const float4*)(pb + ((size_t)b * A_ + a) * 4);
        float ci = ciou_f(g0, g1, g2, g3, p.x * s, p.y * s, p.z * s, p.w * s);
        float ov = fmaxf(ci, 0.f);
        float al = 0.f;
        if (ov > 0.f) {
            float sc = scores[((size_t)b * A_ + a) * NC_ + lab];
            float bs = 1.f / (1.f + __expf(-sc));
            float o2 = ov * ov;
            al = sqrtf(bs) * o2 * o2 * o2;     // bs^0.5 * ov^6
        }
        unsigned long long pkd = ((unsigned long long)__float_as_uint(al) << 32)
                                 | (unsigned)(~(unsigned)a);
        if (pkd > t[TOPK_ - 1]) {
            unsigned long long cv = pkd;
#pragma unroll
            for (int k = 0; k < TOPK_; k++) {
                bool g = cv > t[k];
                unsigned long long o = t[k];
                t[k] = g ? cv : o;
                cv   = g ? o : cv;
            }
        }
    }

    unsigned long long mysel = 0ull;
#pragma unroll
    for (int k = 0; k < TOPK_; k++) {
        unsigned long long w = t[0];
#pragma unroll
        for (int off = 32; off >= 1; off >>= 1) {
            unsigned long long o = shflxor_u64(w, off);
            if (o > w) w = o;
        }
        if (lane == k) mysel = w;
        if (w != 0ull && t[0] == w) {
#pragma unroll
            for (int q = 0; q < TOPK_ - 1; q++) t[q] = t[q + 1];
            t[TOPK_ - 1] = 0ull;
        }
    }

    float sval = __uint_as_float((unsigned)(mysel >> 32));
    int   sidx = (int)(~(unsigned)mysel);
    unsigned int bit = 1u << (m & 31);
    int word = (m >= 32) ? 1 : 0;
    bool keep = (lane < TOPK_) && (sval > EPS_);
    if (keep) atomicOr(&abits[2 * ((size_t)b * A_ + sidx) + word], bit);
    unsigned long long kb = __ballot(keep);
    if (lane == 0 && __popcll(kb) < TOPK_) {
        float ax = 4.f, ay = 4.f;               // anchor 0 center in pixels
        if ((ax - g0) > EPS_ && (ay - g1) > EPS_ && (g2 - ax) > EPS_ && (g3 - ay) > EPS_)
            atomicOr(&abits[2 * ((size_t)b * A_) + word], bit);
    }
}

// ------------------------------------------- K3: resolve + per-anchor (ov,al) + per-gt maxima
__global__ __launch_bounds__(256) void k_R(
    const unsigned int* __restrict__ abits, const float* __restrict__ pb,
    const float* __restrict__ scores, const float* __restrict__ gt,
    const float* __restrict__ mgt, const int* __restrict__ glab,
    int* __restrict__ tgti, float* __restrict__ alv,
    int* __restrict__ pa_g, int* __restrict__ po_g) {
    int idx = blockIdx.x * blockDim.x + threadIdx.x;
    if (idx >= B_ * A_) return;
    unsigned int lo = abits[2 * idx], hi = abits[2 * idx + 1];
    int fg = __popc(lo) + __popc(hi);
    if (fg == 0) { tgti[idx] = -1; return; }
    int b = idx / A_, a = idx % A_;
    int tgt; float ov;
    if (fg > 1) {
        float bv = -1.f; tgt = 0;
        for (int m = 0; m < M_; m++) {
            int bmi = b * M_ + m;
            float v = 0.f;
            if (mgt[bmi] > 0.f)
                v = ov_at2(pb, gt[bmi * 4], gt[bmi * 4 + 1], gt[bmi * 4 + 2], gt[bmi * 4 + 3], b, a);
            if (v > bv) { bv = v; tgt = m; }    // first max, like jnp.argmax
        }
        ov = fmaxf(bv, 0.f);
    } else {
        tgt = lo ? (__ffs(lo) - 1) : (32 + __ffs(hi) - 1);
        int bmi = b * M_ + tgt;
        ov = ov_at2(pb, gt[bmi * 4], gt[bmi * 4 + 1], gt[bmi * 4 + 2], gt[bmi * 4 + 3], b, a);
    }
    float al = 0.f;
    if (ov > 0.f) {
        int lab = glab[b * M_ + tgt];
        float sc = scores[(size_t)idx * NC_ + lab];
        float bs = 1.f / (1.f + __expf(-sc));
        float o2 = ov * ov;
        al = sqrtf(bs) * o2 * o2 * o2;
    }
    tgti[idx] = tgt;
    alv[idx] = al;
    int bmi = b * M_ + tgt;
    atomicMax(&pa_g[bmi], __float_as_int(al));   // fire-and-forget
    atomicMax(&po_g[bmi], __float_as_int(ov));
}

// ------------------------------------------- K4: norm + tss + (-x*t) + CIoU + DFL, one pass
__global__ __launch_bounds__(256) void k_S(
    const int* __restrict__ tgti, const float* __restrict__ alv,
    const int* __restrict__ pa_g, const int* __restrict__ po_g,
    const float* __restrict__ scores, const float* __restrict__ pb,
    const float* __restrict__ gt, const int* __restrict__ glab,
    const float* __restrict__ distri, float* __restrict__ acc) {
    int idx = blockIdx.x * blockDim.x + threadIdx.x;
    float ts = 0.f, cs = 0.f, liou = 0.f, ldfl = 0.f;
    if (idx < B_ * A_) {
        int tgt = tgti[idx];
        if (tgt >= 0) {
            int b = idx / A_, a = idx % A_;
            int bmi = b * M_ + tgt;
            float al = alv[idx];
            float pa = __int_as_float(pa_g[bmi]);
            float po = __int_as_float(po_g[bmi]);
            float nv = al * po / (pa + EPS_);
            ts = nv;
            int lab = max(glab[bmi], 0);
            float sc = scores[(size_t)idx * NC_ + lab];
            cs = -sc * nv;
            // CIoU
            float ax, ay, s; anchor_of(a, ax, ay, s);
            const float* g = gt + (size_t)bmi * 4;
            float t0 = g[0] / s, t1 = g[1] / s, t2 = g[2] / s, t3 = g[3] / s;
            const float4 p = *(const float4*)(pb + (size_t)idx * 4);
            float iou = ciou_f(p.x, p.y, p.z, p.w, t0, t1, t2, t3);
            liou = (1.f - iou) * nv;
            // DFL
            float tg[4] = { ax - t0, ay - t1, t2 - ax, t3 - ay };
            const float* dd = distri + (size_t)idx * 64;
            float dfl = 0.f;
#pragma unroll
            for (int sd = 0; sd < 4; sd++) {
                float tvv = fminf(fmaxf(tg[sd], 0.f), 14.99f);
                int tl = (int)tvv;
                float wl = (float)(tl + 1) - tvv;
                float wr = 1.f - wl;
                const float* xx = dd + sd * 16;
                float mx = xx[0];
#pragma unroll
                for (int j = 1; j < 16; j++) mx = fmaxf(mx, xx[j]);
                float se = 0.f;
#pragma unroll
                for (int j = 0; j < 16; j++) se += __expf(xx[j] - mx);
                float lse = mx + __logf(se);
                dfl += (lse - xx[tl]) * wl + (lse - xx[tl + 1]) * wr;
            }
            ldfl = dfl * 0.25f * nv;
        }
    }
    __shared__ float r0[256], r1[256], r2[256], r3[256];
    int tid = threadIdx.x;
    r0[tid] = ts; r1[tid] = cs; r2[tid] = liou; r3[tid] = ldfl;
    __syncthreads();
    for (int s = 128; s > 0; s >>= 1) {
        if (tid < s) {
            r0[tid] += r0[tid + s]; r1[tid] += r1[tid + s];
            r2[tid] += r2[tid + s]; r3[tid] += r3[tid + s];
        }
        __syncthreads();
    }
    if (tid == 0) {
        atomicAdd(&acc[0], r0[0]); atomicAdd(&acc[1], r1[0]);
        atomicAdd(&acc[2], r2[0]); atomicAdd(&acc[3], r3[0]);
    }
}

// ------------------------------------------- K5: finalize
__global__ void k_final(const float* __restrict__ acc, float* __restrict__ out) {
    if (threadIdx.x == 0) {
        float tss = fmaxf(acc[0], 1.f);
        out[0] = acc[2] / tss * 7.5f;   // loss_iou * HYP_BOX
        out[1] = acc[1] / tss * 0.5f;   // loss_cls * HYP_CLS
        out[2] = acc[3] / tss * 1.5f;   // loss_dfl * HYP_DFL
    }
}

extern "C" void kernel_launch(void* const* d_in, const int* in_sizes, int n_in,
                              void* d_out, int out_size, void* d_ws, size_t ws_size,
                              hipStream_t stream) {
    const float* scores = (const float*)d_in[0];   // [B,A,NC]
    const float* distri = (const float*)d_in[1];   // [B,A,64]
    const float* gtb    = (const float*)d_in[4];   // [B,M,4] (pixels)
    const float* mgt    = (const float*)d_in[5];   // [B,M]
    const int*   glab   = (const int*)d_in[6];     // [B,M]
    float* out = (float*)d_out;

    // workspace layout (~9 MiB)
    float* pb    = (float*)d_ws;                            // B*A*4
    float* alv   = pb + (size_t)B_ * A_ * 4;                // B*A
    int*   tgti  = (int*)(alv + (size_t)B_ * A_);           // B*A
    float* acc   = (float*)(tgti + (size_t)B_ * A_);        // 4        --+
    int*   pa_g  = (int*)(acc + 4);                         // B*M        | zeroed
    int*   po_g  = pa_g + B_ * M_;                          // B*M        | region
    unsigned int* abits = (unsigned int*)(po_g + B_ * M_);  // B*A*2    --+

    size_t zero_bytes = (4 + 2 * B_ * M_) * sizeof(int)
                        + (size_t)B_ * A_ * 2 * sizeof(unsigned int);
    hipMemsetAsync(acc, 0, zero_bytes, stream);

    k_stream<<<1024, 256, 0, stream>>>((const float4*)distri, (const float4*)scores, pb, acc);
    k_aligntopk<<<B_ * M_, 64, 0, stream>>>(scores, pb, gtb, mgt, glab, abits);
    k_R<<<1050, 256, 0, stream>>>(abits, pb, scores, gtb, mgt, glab, tgti, alv, pa_g, po_g);
    k_S<<<1050, 256, 0, stream>>>(tgti, alv, pa_g, po_g, scores, pb, gtb, glab, distri, acc);
    k_final<<<1, 64, 0, stream>>>(acc, out);
    (void)in_sizes; (void)n_in; (void)out_size; (void)ws_size;
}

// Round 7
// 286.337 us; speedup vs baseline: 2.0941x; 1.0252x over previous
//
#include <hip/hip_runtime.h>
#include <math.h>

#define B_    32
#define A_    8400
#define M_    40
#define NC_   80
#define TOPK_ 10
#define EPS_  1e-9f

// ---------------------------------------------------------------- CIoU
__device__ __forceinline__ float ciou_f(float b1x1, float b1y1, float b1x2, float b1y2,
                                        float b2x1, float b2y1, float b2x2, float b2y2) {
    const float eps = 1e-7f;
    float w1 = b1x2 - b1x1, h1 = b1y2 - b1y1 + eps;
    float w2 = b2x2 - b2x1, h2 = b2y2 - b2y1 + eps;
    float iw = fminf(b1x2, b2x2) - fmaxf(b1x1, b2x1);
    float ih = fminf(b1y2, b2y2) - fmaxf(b1y1, b2y1);
    float inter = fmaxf(iw, 0.f) * fmaxf(ih, 0.f);
    float uni = w1 * h1 + w2 * h2 - inter + eps;
    float iou = inter / uni;
    float cw = fmaxf(b1x2, b2x2) - fminf(b1x1, b2x1);
    float ch = fmaxf(b1y2, b2y2) - fminf(b1y1, b2y1);
    float c2 = cw * cw + ch * ch + eps;
    float dx = b2x1 + b2x2 - b1x1 - b1x2;
    float dy = b2y1 + b2y2 - b1y1 - b1y2;
    float rho2 = (dx * dx + dy * dy) * 0.25f;
    float da = atanf(w2 / h2) - atanf(w1 / h1);
    float v = 0.4052847345693511f * da * da;       // 4/pi^2
    float alpha = v / (v - iou + 1.f + eps);
    return iou - (rho2 / c2 + v * alpha);
}

// closed-form anchor: grid-unit center (ax,ay) and stride s for anchor index a
__device__ __forceinline__ void anchor_of(int a, float& ax, float& ay, float& s) {
    if (a < 6400)      { s = 8.f;  int r = a;        ax = (float)(r % 80) + 0.5f; ay = (float)(r / 80) + 0.5f; }
    else if (a < 8000) { s = 16.f; int r = a - 6400; ax = (float)(r % 40) + 0.5f; ay = (float)(r / 40) + 0.5f; }
    else               { s = 32.f; int r = a - 8000; ax = (float)(r % 20) + 0.5f; ay = (float)(r / 20) + 0.5f; }
}

// masked overlap at (b, gt-box g, anchor a); 0 if anchor center outside box
__device__ __forceinline__ float ov_at2(const float* __restrict__ pb,
                                        float g0, float g1, float g2, float g3,
                                        int b, int a) {
    float ax, ay, s; anchor_of(a, ax, ay, s);
    float axp = ax * s, ayp = ay * s;
    if (!((axp - g0) > EPS_ && (ayp - g1) > EPS_ && (g2 - axp) > EPS_ && (g3 - ayp) > EPS_))
        return 0.f;
    const float4 p = *(const float4*)(pb + ((size_t)b * A_ + a) * 4);
    float c = ciou_f(g0, g1, g2, g3, p.x * s, p.y * s, p.z * s, p.w * s);
    return fmaxf(c, 0.f);
}

__device__ __forceinline__ unsigned long long shflxor_u64(unsigned long long v, int m) {
    int lo = __shfl_xor((int)(unsigned)(v & 0xffffffffull), m, 64);
    int hi = __shfl_xor((int)(unsigned)(v >> 32), m, 64);
    return ((unsigned long long)(unsigned)hi << 32) | (unsigned)lo;
}

// quad-cooperative 16-bin softmax-expectation; f is the float4 index
__device__ __forceinline__ void dfl_quad(float4 v, int f, float* __restrict__ pb) {
    int q = f & 3;
    float e0 = __expf(v.x), e1 = __expf(v.y), e2 = __expf(v.z), e3 = __expf(v.w);
    float se = e0 + e1 + e2 + e3;
    float sd = e1 + 2.f * e2 + 3.f * e3 + (float)(4 * q) * se;
    se += __shfl_xor(se, 1, 64); se += __shfl_xor(se, 2, 64);
    sd += __shfl_xor(sd, 1, 64); sd += __shfl_xor(sd, 2, 64);
    float dist = sd / se;
    float d1 = __shfl_down(dist, 4, 64);
    float d2 = __shfl_down(dist, 8, 64);
    float d3 = __shfl_down(dist, 12, 64);
    if ((f & 15) == 0) {
        int aidx = f >> 4;
        int a = aidx % A_;
        float ax, ay, s; anchor_of(a, ax, ay, s);
        ((float4*)pb)[aidx] = make_float4(ax - dist, ay - d1, ax + d2, ay + d3);
    }
}

__device__ __forceinline__ float bce4(float4 x) {
    return fmaxf(x.x, 0.f) + __logf(1.f + __expf(-fabsf(x.x)))
         + fmaxf(x.y, 0.f) + __logf(1.f + __expf(-fabsf(x.y)))
         + fmaxf(x.z, 0.f) + __logf(1.f + __expf(-fabsf(x.z)))
         + fmaxf(x.w, 0.f) + __logf(1.f + __expf(-fabsf(x.w)));
}

// ------------------------------------------- K1: init + DFL-decode + streaming BCE
__global__ void k_stream(const float4* __restrict__ d4,
                         const float4* __restrict__ s4,
                         float* __restrict__ pb,
                         unsigned long long* __restrict__ abits64,
                         unsigned long long* __restrict__ ovmax,
                         float* __restrict__ acc) {
    const int tid0 = blockIdx.x * blockDim.x + threadIdx.x;
    const int nthr = gridDim.x * blockDim.x;           // multiple of 64
    // ---- part 0: init selection bitmask + overlap-argmax arrays (consumed 2 kernels later)
    for (int i = tid0; i < B_ * A_; i += nthr) {
        abits64[i] = 0ull;
        ovmax[i] = 0x00000000FFFFFFFFull;              // (ov=0.0, m=0)
    }
    // ---- part A: pred boxes, 4x unrolled (NF4 divisible by 64)
    const int NF4 = B_ * A_ * 16;
    for (int base = tid0; base < NF4; base += 4 * nthr) {
        int f1 = base + nthr, f2 = base + 2 * nthr, f3 = base + 3 * nthr;
        float4 v0 = d4[base];
        float4 v1, v2, v3;
        if (f1 < NF4) v1 = d4[f1];
        if (f2 < NF4) v2 = d4[f2];
        if (f3 < NF4) v3 = d4[f3];
        dfl_quad(v0, base, pb);
        if (f1 < NF4) dfl_quad(v1, f1, pb);
        if (f2 < NF4) dfl_quad(v2, f2, pb);
        if (f3 < NF4) dfl_quad(v3, f3, pb);
    }
    // ---- part B: BCE target-free part over all logits, 4x unrolled
    const int N4 = B_ * A_ * (NC_ / 4);
    float sum = 0.f;
    for (int base = tid0; base < N4; base += 4 * nthr) {
        int f1 = base + nthr, f2 = base + 2 * nthr, f3 = base + 3 * nthr;
        float4 x0 = s4[base];
        float4 x1, x2, x3;
        if (f1 < N4) x1 = s4[f1];
        if (f2 < N4) x2 = s4[f2];
        if (f3 < N4) x3 = s4[f3];
        sum += bce4(x0);
        if (f1 < N4) sum += bce4(x1);
        if (f2 < N4) sum += bce4(x2);
        if (f3 < N4) sum += bce4(x3);
    }
    __shared__ float sh[256];
    sh[threadIdx.x] = sum; __syncthreads();
    for (int s = 128; s > 0; s >>= 1) {
        if (threadIdx.x < s) sh[threadIdx.x] += sh[threadIdx.x + s];
        __syncthreads();
    }
    if (threadIdx.x == 0) atomicAdd(&acc[1], sh[0]);
}

// ------------------------------------------- K2: rect-scan align + wave top-10 + ov-argmax
__global__ __launch_bounds__(64) void k_aligntopk(
    const float* __restrict__ scores, const float* __restrict__ pb,
    const float* __restrict__ gt, const float* __restrict__ mgt,
    const int* __restrict__ glab, unsigned int* __restrict__ abits,
    unsigned long long* __restrict__ ovmax) {
    int bm = blockIdx.x;
    if (mgt[bm] <= 0.f) return;                 // row all-zero: no selection, no fallback
    int b = bm / M_, m = bm % M_;
    int lab = glab[bm];
    const float g0 = gt[bm * 4 + 0], g1 = gt[bm * 4 + 1];
    const float g2 = gt[bm * 4 + 2], g3 = gt[bm * 4 + 3];
    int lane = threadIdx.x;

    const int   Wl[3]  = { 80, 40, 20 };
    const int   Bs[3]  = { 0, 6400, 8000 };
    const float Sl[3]  = { 8.f, 16.f, 32.f };
    int jlo[3], ilo[3], rw[3], cnt[3];
#pragma unroll
    for (int l = 0; l < 3; l++) {
        float s = Sl[l]; int W = Wl[l];
        int jl = max(0, (int)floorf(g0 / s - 0.5f) - 1);
        int jh = min(W - 1, (int)ceilf(g2 / s - 0.5f) + 1);
        int il = max(0, (int)floorf(g1 / s - 0.5f) - 1);
        int ih = min(W - 1, (int)ceilf(g3 / s - 0.5f) + 1);
        int w = jh - jl + 1, h = ih - il + 1;
        jlo[l] = jl; ilo[l] = il; rw[l] = max(w, 0);
        cnt[l] = (w > 0 && h > 0) ? w * h : 0;
    }
    int c01 = cnt[0] + cnt[1];
    int tot = c01 + cnt[2];

    unsigned long long t[TOPK_];
#pragma unroll
    for (int k = 0; k < TOPK_; k++) t[k] = 0ull;

    for (int c = lane; c < tot; c += 64) {
        int l = (c < cnt[0]) ? 0 : ((c < c01) ? 1 : 2);
        int r = c - ((l == 0) ? 0 : ((l == 1) ? cnt[0] : c01));
        int w = rw[l];
        int di = r / w, dj = r - di * w;
        int i = ilo[l] + di, j = jlo[l] + dj;
        float s = Sl[l];
        float ax = ((float)j + 0.5f) * s;
        float ay = ((float)i + 0.5f) * s;
        if (!((ax - g0) > EPS_ && (ay - g1) > EPS_ && (g2 - ax) > EPS_ && (g3 - ay) > EPS_))
            continue;
        int a = Bs[l] + i * Wl[l] + j;
        const float4 p = *(const float4*)(pb + ((size_t)b * A_ + a) * 4);
        float ci = ciou_f(g0, g1, g2, g3, p.x * s, p.y * s, p.z * s, p.w * s);
        float ov = fmaxf(ci, 0.f);
        float al = 0.f;
        if (ov > 0.f) {
            // feed the per-anchor overlap argmax: (ov desc, m asc) as u64 max
            unsigned long long opk = ((unsigned long long)__float_as_uint(ov) << 32)
                                     | (unsigned)(~(unsigned)m);
            atomicMax(&ovmax[(size_t)b * A_ + a], opk);
            float sc = scores[((size_t)b * A_ + a) * NC_ + lab];
            float bs = 1.f / (1.f + __expf(-sc));
            float o2 = ov * ov;
            al = sqrtf(bs) * o2 * o2 * o2;     // bs^0.5 * ov^6
        }
        unsigned long long pkd = ((unsigned long long)__float_as_uint(al) << 32)
                                 | (unsigned)(~(unsigned)a);
        if (pkd > t[TOPK_ - 1]) {
            unsigned long long cv = pkd;
#pragma unroll
            for (int k = 0; k < TOPK_; k++) {
                bool g = cv > t[k];
                unsigned long long o = t[k];
                t[k] = g ? cv : o;
                cv   = g ? o : cv;
            }
        }
    }

    unsigned long long mysel = 0ull;
#pragma unroll
    for (int k = 0; k < TOPK_; k++) {
        unsigned long long w = t[0];
#pragma unroll
        for (int off = 32; off >= 1; off >>= 1) {
            unsigned long long o = shflxor_u64(w, off);
            if (o > w) w = o;
        }
        if (lane == k) mysel = w;
        if (w != 0ull && t[0] == w) {
#pragma unroll
            for (int q = 0; q < TOPK_ - 1; q++) t[q] = t[q + 1];
            t[TOPK_ - 1] = 0ull;
        }
    }

    float sval = __uint_as_float((unsigned)(mysel >> 32));
    int   sidx = (int)(~(unsigned)mysel);
    unsigned int bit = 1u << (m & 31);
    int word = (m >= 32) ? 1 : 0;
    bool keep = (lane < TOPK_) && (sval > EPS_);
    if (keep) atomicOr(&abits[2 * ((size_t)b * A_ + sidx) + word], bit);
    unsigned long long kb = __ballot(keep);
    if (lane == 0 && __popcll(kb) < TOPK_) {
        float ax = 4.f, ay = 4.f;               // anchor 0 center in pixels
        if ((ax - g0) > EPS_ && (ay - g1) > EPS_ && (g2 - ax) > EPS_ && (g3 - ay) > EPS_)
            atomicOr(&abits[2 * ((size_t)b * A_) + word], bit);
    }
}

// ------------------------------------------- K3: resolve + per-anchor (ov,al) + per-gt maxima
__global__ __launch_bounds__(256) void k_R(
    const unsigned int* __restrict__ abits,
    const unsigned long long* __restrict__ ovmax,
    const float* __restrict__ pb,
    const float* __restrict__ scores, const float* __restrict__ gt,
    const int* __restrict__ glab,
    int* __restrict__ tgti, float* __restrict__ alv,
    int* __restrict__ pa_g, int* __restrict__ po_g) {
    int idx = blockIdx.x * blockDim.x + threadIdx.x;
    if (idx >= B_ * A_) return;
    unsigned int lo = abits[2 * idx], hi = abits[2 * idx + 1];
    int fg = __popc(lo) + __popc(hi);
    if (fg == 0) { tgti[idx] = -1; return; }
    int b = idx / A_, a = idx % A_;
    int tgt; float ov;
    if (fg > 1) {
        unsigned long long pk = ovmax[idx];    // precomputed argmax over masked overlaps
        tgt = (int)(~(unsigned)(pk & 0xffffffffull));
        ov  = __uint_as_float((unsigned)(pk >> 32));
    } else {
        tgt = lo ? (__ffs(lo) - 1) : (32 + __ffs(hi) - 1);
        int bmi = b * M_ + tgt;
        ov = ov_at2(pb, gt[bmi * 4], gt[bmi * 4 + 1], gt[bmi * 4 + 2], gt[bmi * 4 + 3], b, a);
    }
    float al = 0.f;
    if (ov > 0.f) {
        int lab = glab[b * M_ + tgt];
        float sc = scores[(size_t)idx * NC_ + lab];
        float bs = 1.f / (1.f + __expf(-sc));
        float o2 = ov * ov;
        al = sqrtf(bs) * o2 * o2 * o2;
    }
    tgti[idx] = tgt;
    alv[idx] = al;
    int bmi = b * M_ + tgt;
    atomicMax(&pa_g[bmi], __float_as_int(al));   // fire-and-forget
    atomicMax(&po_g[bmi], __float_as_int(ov));
}

// ------------------------------------------- K4: norm + tss + (-x*t) + CIoU + DFL, one pass
__global__ __launch_bounds__(256) void k_S(
    const int* __restrict__ tgti, const float* __restrict__ alv,
    const int* __restrict__ pa_g, const int* __restrict__ po_g,
    const float* __restrict__ scores, const float* __restrict__ pb,
    const float* __restrict__ gt, const int* __restrict__ glab,
    const float* __restrict__ distri, float* __restrict__ acc) {
    int idx = blockIdx.x * blockDim.x + threadIdx.x;
    float ts = 0.f, cs = 0.f, liou = 0.f, ldfl = 0.f;
    if (idx < B_ * A_) {
        int tgt = tgti[idx];
        if (tgt >= 0) {
            int b = idx / A_, a = idx % A_;
            int bmi = b * M_ + tgt;
            float al = alv[idx];
            float pa = __int_as_float(pa_g[bmi]);
            float po = __int_as_float(po_g[bmi]);
            float nv = al * po / (pa + EPS_);
            ts = nv;
            int lab = max(glab[bmi], 0);
            float sc = scores[(size_t)idx * NC_ + lab];
            cs = -sc * nv;
            // CIoU
            float ax, ay, s; anchor_of(a, ax, ay, s);
            const float* g = gt + (size_t)bmi * 4;
            float t0 = g[0] / s, t1 = g[1] / s, t2 = g[2] / s, t3 = g[3] / s;
            const float4 p = *(const float4*)(pb + (size_t)idx * 4);
            float iou = ciou_f(p.x, p.y, p.z, p.w, t0, t1, t2, t3);
            liou = (1.f - iou) * nv;
            // DFL
            float tg[4] = { ax - t0, ay - t1, t2 - ax, t3 - ay };
            const float* dd = distri + (size_t)idx * 64;
            float dfl = 0.f;
#pragma unroll
            for (int sd = 0; sd < 4; sd++) {
                float tvv = fminf(fmaxf(tg[sd], 0.f), 14.99f);
                int tl = (int)tvv;
                float wl = (float)(tl + 1) - tvv;
                float wr = 1.f - wl;
                const float* xx = dd + sd * 16;
                float mx = xx[0];
#pragma unroll
                for (int j = 1; j < 16; j++) mx = fmaxf(mx, xx[j]);
                float se = 0.f;
#pragma unroll
                for (int j = 0; j < 16; j++) se += __expf(xx[j] - mx);
                float lse = mx + __logf(se);
                dfl += (lse - xx[tl]) * wl + (lse - xx[tl + 1]) * wr;
            }
            ldfl = dfl * 0.25f * nv;
        }
    }
    __shared__ float r0[256], r1[256], r2[256], r3[256];
    int tid = threadIdx.x;
    r0[tid] = ts; r1[tid] = cs; r2[tid] = liou; r3[tid] = ldfl;
    __syncthreads();
    for (int s = 128; s > 0; s >>= 1) {
        if (tid < s) {
            r0[tid] += r0[tid + s]; r1[tid] += r1[tid + s];
            r2[tid] += r2[tid + s]; r3[tid] += r3[tid + s];
        }
        __syncthreads();
    }
    if (tid == 0) {
        atomicAdd(&acc[0], r0[0]); atomicAdd(&acc[1], r1[0]);
        atomicAdd(&acc[2], r2[0]); atomicAdd(&acc[3], r3[0]);
    }
}

// ------------------------------------------- K5: finalize
__global__ void k_final(const float* __restrict__ acc, float* __restrict__ out) {
    if (threadIdx.x == 0) {
        float tss = fmaxf(acc[0], 1.f);
        out[0] = acc[2] / tss * 7.5f;   // loss_iou * HYP_BOX
        out[1] = acc[1] / tss * 0.5f;   // loss_cls * HYP_CLS
        out[2] = acc[3] / tss * 1.5f;   // loss_dfl * HYP_DFL
    }
}

extern "C" void kernel_launch(void* const* d_in, const int* in_sizes, int n_in,
                              void* d_out, int out_size, void* d_ws, size_t ws_size,
                              hipStream_t stream) {
    const float* scores = (const float*)d_in[0];   // [B,A,NC]
    const float* distri = (const float*)d_in[1];   // [B,A,64]
    const float* gtb    = (const float*)d_in[4];   // [B,M,4] (pixels)
    const float* mgt    = (const float*)d_in[5];   // [B,M]
    const int*   glab   = (const int*)d_in[6];     // [B,M]
    float* out = (float*)d_out;

    // workspace layout (~11 MiB); ovmax first for 8-byte alignment
    unsigned long long* ovmax = (unsigned long long*)d_ws;          // B*A u64
    float* pb    = (float*)(ovmax + (size_t)B_ * A_);               // B*A*4
    float* alv   = pb + (size_t)B_ * A_ * 4;                        // B*A
    int*   tgti  = (int*)(alv + (size_t)B_ * A_);                   // B*A
    float* acc   = (float*)(tgti + (size_t)B_ * A_);                // 4    --+ zeroed
    int*   pa_g  = (int*)(acc + 4);                                 // B*M    |
    int*   po_g  = pa_g + B_ * M_;                                  // B*M  --+
    unsigned int* abits = (unsigned int*)(po_g + B_ * M_);          // B*A*2 (init in k_stream)

    size_t zero_bytes = (4 + 2 * B_ * M_) * sizeof(int);
    hipMemsetAsync(acc, 0, zero_bytes, stream);

    k_stream<<<2048, 256, 0, stream>>>((const float4*)distri, (const float4*)scores, pb,
                                       (unsigned long long*)abits, ovmax, acc);
    k_aligntopk<<<B_ * M_, 64, 0, stream>>>(scores, pb, gtb, mgt, glab, abits, ovmax);
    k_R<<<1050, 256, 0, stream>>>(abits, ovmax, pb, scores, gtb, glab, tgti, alv, pa_g, po_g);
    k_S<<<1050, 256, 0, stream>>>(tgti, alv, pa_g, po_g, scores, pb, gtb, glab, distri, acc);
    k_final<<<1, 64, 0, stream>>>(acc, out);
    (void)in_sizes; (void)n_in; (void)out_size; (void)ws_size;
}